// Round 1
// baseline (3221.668 us; speedup 1.0000x reference)
//
#include <hip/hip_runtime.h>
#include <cstdint>
#include <cstddef>

#define NB 32
#define NN 2048
#define ND 512
#define NH 512
#define NC 512
#define ROWS (NB*NN)                 // 65536

// ---------------- threefry2x32-20 (JAX partitionable scheme) ----------------
__device__ __forceinline__ unsigned rotl32(unsigned x, int d){ return (x<<d)|(x>>(32-d)); }

__device__ __forceinline__ unsigned threefry_xor(unsigned k0, unsigned k1, unsigned c0, unsigned c1){
  unsigned ks2 = 0x1BD11BDAu ^ k0 ^ k1;
  unsigned x0 = c0 + k0, x1 = c1 + k1;
#define TF_RND(r) { x0 += x1; x1 = rotl32(x1,(r)); x1 ^= x0; }
  TF_RND(13) TF_RND(15) TF_RND(26) TF_RND(6)
  x0 += k1;  x1 += ks2 + 1u;
  TF_RND(17) TF_RND(29) TF_RND(16) TF_RND(24)
  x0 += ks2; x1 += k0 + 2u;
  TF_RND(13) TF_RND(15) TF_RND(26) TF_RND(6)
  x0 += k0;  x1 += k1 + 3u;
  TF_RND(17) TF_RND(29) TF_RND(16) TF_RND(24)
  x0 += k1;  x1 += ks2 + 4u;
  TF_RND(13) TF_RND(15) TF_RND(26) TF_RND(6)
  x0 += ks2; x1 += k0 + 5u;
#undef TF_RND
  return x0 ^ x1;
}

// uniform(-1+2^-24, 1) -> sqrt(2)*erfinv(u), matching XLA f32 (Giles poly, log1p form)
__device__ __forceinline__ float bits_to_normal(unsigned bits){
  float f = __uint_as_float((bits >> 9) | 0x3f800000u) - 1.0f;   // [0,1)
  const float lo = -0.99999994f;                                  // nextafterf(-1,0)
  float u = fmaxf(lo, fmaf(f, 2.0f, lo));                         // (hi-lo) rounds to 2.0f
  float w = -log1pf(-(u*u));
  float p;
  if (w < 5.0f){
    w -= 2.5f;
    p =            2.81022636e-08f;
    p = fmaf(p, w, 3.43273939e-07f);
    p = fmaf(p, w, -3.5233877e-06f);
    p = fmaf(p, w, -4.39150654e-06f);
    p = fmaf(p, w, 0.00021858087f);
    p = fmaf(p, w, -0.00125372503f);
    p = fmaf(p, w, -0.00417768164f);
    p = fmaf(p, w, 0.246640727f);
    p = fmaf(p, w, 1.50140941f);
  } else {
    w = sqrtf(w) - 3.0f;
    p =            -0.000200214257f;
    p = fmaf(p, w, 0.000100950558f);
    p = fmaf(p, w, 0.00134934322f);
    p = fmaf(p, w, -0.00367342844f);
    p = fmaf(p, w, 0.00573950773f);
    p = fmaf(p, w, -0.0076224613f);
    p = fmaf(p, w, 0.00943887047f);
    p = fmaf(p, w, 1.00167406f);
    p = fmaf(p, w, 2.83297682f);
  }
  return 1.4142135623730951f * (p * u);
}

__global__ void __launch_bounds__(256) rng_kernel(float* __restrict__ s){
  unsigned i = blockIdx.x * 256u + threadIdx.x;
  s[i] = bits_to_normal(threefry_xor(0u, 42u, 0u, i));
}

// ---------------- cluster counts (mask dtype auto-detect) ----------------
__global__ void __launch_bounds__(256) counts_kernel(const unsigned char* __restrict__ mraw,
                                                     int* __restrict__ cnum){
  __shared__ int red[256];
  int b = blockIdx.x, tid = threadIdx.x;
  unsigned char b0 = mraw[0], b1 = mraw[1];   // mask[0][0..1] are True
  int cnt = 0;
  if (b0 == 1 && b1 == 1){                    // bool / int8, 1 byte per elem
    const unsigned char* p = mraw + (size_t)b * NN;
    for (int i = tid; i < NN; i += 256) cnt += (p[i] != 0);
  } else if (b0 == 1){                        // int32
    const int* p = (const int*)mraw + (size_t)b * NN;
    for (int i = tid; i < NN; i += 256) cnt += (p[i] != 0);
  } else {                                    // float32
    const float* p = (const float*)mraw + (size_t)b * NN;
    for (int i = tid; i < NN; i += 256) cnt += (p[i] != 0.0f);
  }
  red[tid] = cnt; __syncthreads();
  for (int off = 128; off; off >>= 1){ if (tid < off) red[tid] += red[tid+off]; __syncthreads(); }
  if (tid == 0) cnum[b] = red[0] >> 2;        // floor(node_num*0.25)
}

// ---------------- y = adj @ x  (adj ~1% dense, values {0,1}) ----------------
__global__ void __launch_bounds__(256) spmm_kernel(const float* __restrict__ adj,
                                                   const float* __restrict__ x,
                                                   float* __restrict__ y){
  __shared__ int   idxs[NN];
  __shared__ float vals[NN];
  __shared__ int   scan[256];
  int row = blockIdx.x;             // b*NN + n
  int b = row >> 11;
  int tid = threadIdx.x;
  const float* arow = adj + (size_t)row * NN;
  float v[8];
  *(float4*)&v[0] = *(const float4*)(arow + tid*8);
  *(float4*)&v[4] = *(const float4*)(arow + tid*8 + 4);
  int lc = 0;
  #pragma unroll
  for (int j=0;j<8;j++) lc += (v[j] != 0.0f);
  scan[tid] = lc; __syncthreads();
  for (int off=1; off<256; off<<=1){          // Hillis-Steele inclusive scan
    int t = (tid >= off) ? scan[tid-off] : 0;
    __syncthreads();
    scan[tid] += t;
    __syncthreads();
  }
  int pos = scan[tid] - lc;
  int total = scan[255];
  #pragma unroll
  for (int j=0;j<8;j++){
    if (v[j] != 0.0f){ idxs[pos] = tid*8 + j; vals[pos] = v[j]; pos++; }
  }
  __syncthreads();
  float acc0 = 0.f, acc1 = 0.f;
  const float* xb = x + (size_t)b * NN * ND;
  for (int j=0;j<total;j++){
    int m = idxs[j]; float a = vals[j];
    acc0 = fmaf(a, xb[(size_t)m*ND + tid      ], acc0);
    acc1 = fmaf(a, xb[(size_t)m*ND + tid + 256], acc1);
  }
  float* yr = y + (size_t)row * ND;
  yr[tid] = acc0; yr[tid+256] = acc1;
}

// ---------------- f32 GEMM, 128x128x16 tile, 256 thr, 8x8/thread ----------------
// C(m,n) = sum_k Aacc(m,k)*Bacc(k,n);  TA: A[k*lda+m]  else A[m*lda+k]
//                                      TB: B[n*ldb+k]  else B[k*ldb+n]
// EPI 0: store; 1: relu(acc+bias[n]); 2: store S2(m,n)+acc
template<bool TA, bool TB, int EPI>
__global__ void __launch_bounds__(256) gemm_kernel(
    const float* __restrict__ A, const float* __restrict__ B, float* __restrict__ C,
    const float* __restrict__ S2, const float* __restrict__ bias,
    int M, int N, int K, int lda, int ldb, int ldc,
    long sA, long sB, long sC)
{
  int bz = blockIdx.z;
  A += (long)bz * sA; B += (long)bz * sB; C += (long)bz * sC;
  if constexpr (EPI == 2) S2 += (long)bz * sC;
  int m0 = blockIdx.x * 128, n0 = blockIdx.y * 128;
  __shared__ float As[16][132];
  __shared__ float Bs[16][132];
  int tid = threadIdx.x;
  int tx = tid & 15, ty = tid >> 4;
  int mr = ty*4, nc = tx*4;
  float acc[8][8] = {};
  for (int k0 = 0; k0 < K; k0 += 16){
    if constexpr (!TA){   // A row-major MxK: tile 128x16
      int kg = (tid & 3)*4, r = tid >> 2;
      #pragma unroll
      for (int h=0; h<2; h++){
        int rr = r + h*64;
        float4 v = *(const float4*)(A + (size_t)(m0+rr)*lda + k0 + kg);
        As[kg+0][rr] = v.x; As[kg+1][rr] = v.y; As[kg+2][rr] = v.z; As[kg+3][rr] = v.w;
      }
    } else {              // A stored KxM: tile 16x128, direct copy
      int kk = tid >> 5, cc = (tid & 31)*4;
      #pragma unroll
      for (int h=0; h<2; h++){
        int rr = kk + h*8;
        *(float4*)&As[rr][cc] = *(const float4*)(A + (size_t)(k0+rr)*lda + m0 + cc);
      }
    }
    if constexpr (!TB){   // B row-major KxN: tile 16x128, direct copy
      int kk = tid >> 5, cc = (tid & 31)*4;
      #pragma unroll
      for (int h=0; h<2; h++){
        int rr = kk + h*8;
        *(float4*)&Bs[rr][cc] = *(const float4*)(B + (size_t)(k0+rr)*ldb + n0 + cc);
      }
    } else {              // B stored NxK: tile 128x16, transpose on store
      int kg = (tid & 3)*4, r = tid >> 2;
      #pragma unroll
      for (int h=0; h<2; h++){
        int rr = r + h*64;
        float4 v = *(const float4*)(B + (size_t)(n0+rr)*ldb + k0 + kg);
        Bs[kg+0][rr] = v.x; Bs[kg+1][rr] = v.y; Bs[kg+2][rr] = v.z; Bs[kg+3][rr] = v.w;
      }
    }
    __syncthreads();
    #pragma unroll
    for (int k=0; k<16; k++){
      float a[8], bb[8];
      *(float4*)&a[0]  = *(const float4*)&As[k][mr];
      *(float4*)&a[4]  = *(const float4*)&As[k][mr+64];
      *(float4*)&bb[0] = *(const float4*)&Bs[k][nc];
      *(float4*)&bb[4] = *(const float4*)&Bs[k][nc+64];
      #pragma unroll
      for (int i=0;i<8;i++)
        #pragma unroll
        for (int j=0;j<8;j++)
          acc[i][j] = fmaf(a[i], bb[j], acc[i][j]);
    }
    __syncthreads();
  }
  #pragma unroll
  for (int i=0;i<8;i++){
    int r = m0 + ((i<4) ? (mr + i) : (mr + 60 + i));
    #pragma unroll
    for (int jh=0; jh<2; jh++){
      int c = n0 + nc + jh*64;
      float4 v = make_float4(acc[i][jh*4+0], acc[i][jh*4+1], acc[i][jh*4+2], acc[i][jh*4+3]);
      if constexpr (EPI == 1){
        float4 bv = *(const float4*)(bias + c);
        v.x = fmaxf(v.x + bv.x, 0.f); v.y = fmaxf(v.y + bv.y, 0.f);
        v.z = fmaxf(v.z + bv.z, 0.f); v.w = fmaxf(v.w + bv.w, 0.f);
      } else if constexpr (EPI == 2){
        float4 s2 = *(const float4*)(S2 + (size_t)r*ldc + c);
        v.x += s2.x; v.y += s2.y; v.z += s2.z; v.w += s2.w;
      }
      *(float4*)(C + (size_t)r*ldc + c) = v;
    }
  }
}

// ---------------- masked softmax over c (row = b*NN+n), wave per row ----------------
__global__ void __launch_bounds__(256) softmax_kernel(const float* __restrict__ s,
                                                      float* __restrict__ o,
                                                      const int* __restrict__ cnum){
  int row  = blockIdx.x*4 + (threadIdx.x >> 6);
  int lane = threadIdx.x & 63;
  int b = row >> 11;
  int Kc = cnum[b];
  const float* p = s + (size_t)row * NC;
  float4 v0 = *(const float4*)(p + lane*4);
  float4 v1 = *(const float4*)(p + lane*4 + 256);
  float e[8] = {v0.x,v0.y,v0.z,v0.w,v1.x,v1.y,v1.z,v1.w};
  float m = -3.0e38f;
  #pragma unroll
  for (int j=0;j<8;j++){
    int c = (j<4) ? lane*4 + j : lane*4 + 252 + j;
    if (c < Kc) m = fmaxf(m, e[j]);
  }
  #pragma unroll
  for (int off=32; off; off>>=1) m = fmaxf(m, __shfl_xor(m, off, 64));
  float r[8]; float sum = 0.f;
  #pragma unroll
  for (int j=0;j<8;j++){
    int c = (j<4) ? lane*4 + j : lane*4 + 252 + j;
    r[j] = (c < Kc) ? expf(e[j] - m) : 0.0f;
    sum += r[j];
  }
  #pragma unroll
  for (int off=32; off; off>>=1) sum += __shfl_xor(sum, off, 64);
  float inv = 1.0f / sum;
  float* q = o + (size_t)row * NC;
  *(float4*)(q + lane*4)       = make_float4(r[0]*inv, r[1]*inv, r[2]*inv, r[3]*inv);
  *(float4*)(q + lane*4 + 256) = make_float4(r[4]*inv, r[5]*inv, r[6]*inv, r[7]*inv);
}

// ---------------- squash over h, in-place on xnext (row = b*NC+c) ----------------
__global__ void __launch_bounds__(256) squash_kernel(float* __restrict__ xn){
  int row  = blockIdx.x*4 + (threadIdx.x >> 6);
  int lane = threadIdx.x & 63;
  float* p = xn + (size_t)row * NH;
  float4 v0 = *(const float4*)(p + lane*4);
  float4 v1 = *(const float4*)(p + lane*4 + 256);
  float e[8] = {v0.x,v0.y,v0.z,v0.w,v1.x,v1.y,v1.z,v1.w};
  float ms = 0.f;
  #pragma unroll
  for (int j=0;j<8;j++) ms = fmaf(e[j], e[j], ms);
  #pragma unroll
  for (int off=32; off; off>>=1) ms += __shfl_xor(ms, off, 64);
  float sc = 0.0f;
  if (ms > 0.0f){ float t = ms / (1.0f + ms); sc = t / sqrtf(ms); }
  *(float4*)(p + lane*4)       = make_float4(e[0]*sc, e[1]*sc, e[2]*sc, e[3]*sc);
  *(float4*)(p + lane*4 + 256) = make_float4(e[4]*sc, e[5]*sc, e[6]*sc, e[7]*sc);
}

// ---------------- orchestration ----------------
extern "C" void kernel_launch(void* const* d_in, const int* in_sizes, int n_in,
                              void* d_out, int out_size, void* d_ws, size_t ws_size,
                              hipStream_t stream) {
  const float* x    = (const float*)d_in[0];
  const float* adj  = (const float*)d_in[1];
  const float* W    = (const float*)d_in[2];
  const float* bias = (const float*)d_in[3];
  const unsigned char* mask = (const unsigned char*)d_in[4];
  float* out = (float*)d_out;           // doubles as s~ (softmaxed s) buffer
  char* ws = (char*)d_ws;

  float* s     = (float*)ws;                         // 134217728 B (aliases y)
  float* z     = (float*)(ws + 134217728);           // 134217728 B
  float* xnext = (float*)(ws + 268435456);           //  33554432 B
  int*   cnum  = (int*)  (ws + 301989888);           //       128 B
  float* y     = s;                                  // y lives before s is generated

  counts_kernel<<<NB, 256, 0, stream>>>(mask, cnum);
  spmm_kernel<<<ROWS, 256, 0, stream>>>(adj, x, y);
  // z = relu(y @ W + b)   M=65536 N=512 K=512
  gemm_kernel<false,false,1><<<dim3(512,4,1), 256, 0, stream>>>(
      y, W, z, nullptr, bias, ROWS, NH, ND, ND, NH, NH, 0, 0, 0);
  // s0 = jax.random.normal(key(42))
  rng_kernel<<<(ROWS*NC)/256, 256, 0, stream>>>(s);

  for (int it = 0; it < 3; ++it){
    // s~ = masked_softmax(s)  -> out
    softmax_kernel<<<ROWS/4, 256, 0, stream>>>(s, out, cnum);
    // xnext_raw[c,h] = sum_n s~[n,c] z[n,h]   (per batch)  M=C N=H K=NN
    gemm_kernel<true,false,0><<<dim3(4,4,NB), 256, 0, stream>>>(
        out, z, xnext, nullptr, nullptr, NC, NH, NN, NC, NH, NH,
        (long)NN*NC, (long)NN*NH, (long)NC*NH);
    squash_kernel<<<(NB*NC)/4, 256, 0, stream>>>(xnext);
    // s[n,c] = s~[n,c] + sum_h z[n,h] xnext[c,h]   M=NN N=C K=H
    gemm_kernel<false,true,2><<<dim3(16,4,NB), 256, 0, stream>>>(
        z, xnext, s, out, nullptr, NN, NC, NH, NH, NH, NC,
        (long)NN*NH, (long)NC*NH, (long)NN*NC);
  }
  softmax_kernel<<<ROWS/4, 256, 0, stream>>>(s, out, cnum);
}

// Round 2
// 1742.979 us; speedup vs baseline: 1.8484x; 1.8484x over previous
//
#include <hip/hip_runtime.h>
#include <cstdint>
#include <cstddef>

#define NB 32
#define NN 2048
#define ND 512
#define NH 512
#define NC 512
#define ROWS (NB*NN)                 // 65536

typedef __attribute__((ext_vector_type(8))) short short8v;   // 8 bf16 (4 VGPR)
typedef __attribute__((ext_vector_type(4))) float f32x4;

#define MFMA16(a,b,c) __builtin_amdgcn_mfma_f32_16x16x32_bf16((a),(b),(c),0,0,0)

typedef const __attribute__((address_space(1))) unsigned int* gas_t;
typedef __attribute__((address_space(3))) unsigned int* las_t;

__device__ __forceinline__ void gload16(const void* g, void* l){
  __builtin_amdgcn_global_load_lds((gas_t)g, (las_t)l, 16, 0, 0);
}

// f32 -> bf16 hi/lo split (RNE both).  v ~= h + l, |v-h-l| <= 2^-18 |v|
__device__ __forceinline__ void fsplit(float v, unsigned short& h, unsigned short& l){
  unsigned u = __float_as_uint(v);
  unsigned hb = (u + 0x7FFFu + ((u>>16)&1u)) >> 16;
  float hf = __uint_as_float(hb<<16);
  float r = v - hf;
  unsigned ur = __float_as_uint(r);
  l = (unsigned short)((ur + 0x7FFFu + ((ur>>16)&1u)) >> 16);
  h = (unsigned short)hb;
}

// ---------------- threefry2x32-20 (JAX partitionable scheme) ----------------
__device__ __forceinline__ unsigned rotl32(unsigned x, int d){ return (x<<d)|(x>>(32-d)); }

__device__ __forceinline__ unsigned threefry_xor(unsigned k0, unsigned k1, unsigned c0, unsigned c1){
  unsigned ks2 = 0x1BD11BDAu ^ k0 ^ k1;
  unsigned x0 = c0 + k0, x1 = c1 + k1;
#define TF_RND(r) { x0 += x1; x1 = rotl32(x1,(r)); x1 ^= x0; }
  TF_RND(13) TF_RND(15) TF_RND(26) TF_RND(6)
  x0 += k1;  x1 += ks2 + 1u;
  TF_RND(17) TF_RND(29) TF_RND(16) TF_RND(24)
  x0 += ks2; x1 += k0 + 2u;
  TF_RND(13) TF_RND(15) TF_RND(26) TF_RND(6)
  x0 += k0;  x1 += k1 + 3u;
  TF_RND(17) TF_RND(29) TF_RND(16) TF_RND(24)
  x0 += k1;  x1 += ks2 + 4u;
  TF_RND(13) TF_RND(15) TF_RND(26) TF_RND(6)
  x0 += ks2; x1 += k0 + 5u;
#undef TF_RND
  return x0 ^ x1;
}

__device__ __forceinline__ float bits_to_normal(unsigned bits){
  float f = __uint_as_float((bits >> 9) | 0x3f800000u) - 1.0f;
  const float lo = -0.99999994f;
  float u = fmaxf(lo, fmaf(f, 2.0f, lo));
  float w = -log1pf(-(u*u));
  float p;
  if (w < 5.0f){
    w -= 2.5f;
    p =            2.81022636e-08f;
    p = fmaf(p, w, 3.43273939e-07f);
    p = fmaf(p, w, -3.5233877e-06f);
    p = fmaf(p, w, -4.39150654e-06f);
    p = fmaf(p, w, 0.00021858087f);
    p = fmaf(p, w, -0.00125372503f);
    p = fmaf(p, w, -0.00417768164f);
    p = fmaf(p, w, 0.246640727f);
    p = fmaf(p, w, 1.50140941f);
  } else {
    w = sqrtf(w) - 3.0f;
    p =            -0.000200214257f;
    p = fmaf(p, w, 0.000100950558f);
    p = fmaf(p, w, 0.00134934322f);
    p = fmaf(p, w, -0.00367342844f);
    p = fmaf(p, w, 0.00573950773f);
    p = fmaf(p, w, -0.0076224613f);
    p = fmaf(p, w, 0.00943887047f);
    p = fmaf(p, w, 1.00167406f);
    p = fmaf(p, w, 2.83297682f);
  }
  return 1.4142135623730951f * (p * u);
}

__global__ void __launch_bounds__(256) rng_kernel(float* __restrict__ s){
  unsigned i = blockIdx.x * 256u + threadIdx.x;
  s[i] = bits_to_normal(threefry_xor(0u, 42u, 0u, i));
}

// ---------------- cluster counts ----------------
__global__ void __launch_bounds__(256) counts_kernel(const unsigned char* __restrict__ mraw,
                                                     int* __restrict__ cnum){
  __shared__ int red[256];
  int b = blockIdx.x, tid = threadIdx.x;
  unsigned char b0 = mraw[0], b1 = mraw[1];
  int cnt = 0;
  if (b0 == 1 && b1 == 1){
    const unsigned char* p = mraw + (size_t)b * NN;
    for (int i = tid; i < NN; i += 256) cnt += (p[i] != 0);
  } else if (b0 == 1){
    const int* p = (const int*)mraw + (size_t)b * NN;
    for (int i = tid; i < NN; i += 256) cnt += (p[i] != 0);
  } else {
    const float* p = (const float*)mraw + (size_t)b * NN;
    for (int i = tid; i < NN; i += 256) cnt += (p[i] != 0.0f);
  }
  red[tid] = cnt; __syncthreads();
  for (int off = 128; off; off >>= 1){ if (tid < off) red[tid] += red[tid+off]; __syncthreads(); }
  if (tid == 0) cnum[b] = red[0] >> 2;
}

// ---------------- y = adj @ x, writes split bf16 ----------------
__global__ void __launch_bounds__(256) spmm_kernel(const float* __restrict__ adj,
                                                   const float* __restrict__ x,
                                                   unsigned short* __restrict__ yh,
                                                   unsigned short* __restrict__ yl){
  __shared__ int   idxs[NN];
  __shared__ float vals[NN];
  __shared__ int   scan[256];
  int row = blockIdx.x;
  int b = row >> 11;
  int tid = threadIdx.x;
  const float* arow = adj + (size_t)row * NN;
  float v[8];
  *(float4*)&v[0] = *(const float4*)(arow + tid*8);
  *(float4*)&v[4] = *(const float4*)(arow + tid*8 + 4);
  int lc = 0;
  #pragma unroll
  for (int j=0;j<8;j++) lc += (v[j] != 0.0f);
  scan[tid] = lc; __syncthreads();
  for (int off=1; off<256; off<<=1){
    int t = (tid >= off) ? scan[tid-off] : 0;
    __syncthreads();
    scan[tid] += t;
    __syncthreads();
  }
  int pos = scan[tid] - lc;
  int total = scan[255];
  #pragma unroll
  for (int j=0;j<8;j++){
    if (v[j] != 0.0f){ idxs[pos] = tid*8 + j; vals[pos] = v[j]; pos++; }
  }
  __syncthreads();
  float acc0 = 0.f, acc1 = 0.f;
  const float* xb = x + (size_t)b * NN * ND;
  for (int j=0;j<total;j++){
    int m = idxs[j]; float a = vals[j];
    acc0 = fmaf(a, xb[(size_t)m*ND + tid      ], acc0);
    acc1 = fmaf(a, xb[(size_t)m*ND + tid + 256], acc1);
  }
  unsigned short h,l;
  size_t base = (size_t)row * ND;
  fsplit(acc0,h,l); yh[base+tid]=h;     yl[base+tid]=l;
  fsplit(acc1,h,l); yh[base+tid+256]=h; yl[base+tid+256]=l;
}

// ---------------- W transpose + split: WT[h][d] ----------------
__global__ void __launch_bounds__(256) wsplit_kernel(const float* __restrict__ W,
                                                     unsigned short* __restrict__ WTh,
                                                     unsigned short* __restrict__ WTl){
  __shared__ float t[32][33];
  int bx = blockIdx.x, by = blockIdx.y;
  int x = threadIdx.x & 31, y = threadIdx.x >> 5;
  for (int yy=y; yy<32; yy+=8) t[yy][x] = W[(size_t)(bx*32+yy)*512 + by*32 + x];
  __syncthreads();
  for (int yy=y; yy<32; yy+=8){
    float v = t[x][yy];                     // = W[bx*32+x][by*32+yy]
    unsigned short h,l; fsplit(v,h,l);
    size_t idx = (size_t)(by*32+yy)*512 + bx*32 + x;
    WTh[idx]=h; WTl[idx]=l;
  }
}

// ---------------- masked softmax (in-place f32 + optional split out) ----------------
template<bool SPLIT>
__global__ void __launch_bounds__(256) softmax_kernel(float* __restrict__ s,
                                                      unsigned short* __restrict__ sh,
                                                      unsigned short* __restrict__ sl,
                                                      const int* __restrict__ cnum){
  int row  = blockIdx.x*4 + (threadIdx.x >> 6);
  int lane = threadIdx.x & 63;
  int b = row >> 11;
  int Kc = cnum[b];
  float* p = s + (size_t)row * NC;
  float4 v0 = *(const float4*)(p + lane*4);
  float4 v1 = *(const float4*)(p + lane*4 + 256);
  float e[8] = {v0.x,v0.y,v0.z,v0.w,v1.x,v1.y,v1.z,v1.w};
  float m = -3.0e38f;
  #pragma unroll
  for (int j=0;j<8;j++){
    int c = (j<4) ? lane*4 + j : lane*4 + 252 + j;
    if (c < Kc) m = fmaxf(m, e[j]);
  }
  #pragma unroll
  for (int off=32; off; off>>=1) m = fmaxf(m, __shfl_xor(m, off, 64));
  float r[8]; float sum = 0.f;
  #pragma unroll
  for (int j=0;j<8;j++){
    int c = (j<4) ? lane*4 + j : lane*4 + 252 + j;
    r[j] = (c < Kc) ? expf(e[j] - m) : 0.0f;
    sum += r[j];
  }
  #pragma unroll
  for (int off=32; off; off>>=1) sum += __shfl_xor(sum, off, 64);
  float inv = 1.0f / sum;
  #pragma unroll
  for (int j=0;j<8;j++) r[j] *= inv;
  *(float4*)(p + lane*4)       = make_float4(r[0],r[1],r[2],r[3]);
  *(float4*)(p + lane*4 + 256) = make_float4(r[4],r[5],r[6],r[7]);
  if constexpr (SPLIT){
    unsigned long long ph=0, pl=0, qh=0, ql=0;
    #pragma unroll
    for (int j=0;j<4;j++){
      unsigned short h,l;
      fsplit(r[j],h,l);
      ph |= (unsigned long long)h << (16*j);  pl |= (unsigned long long)l << (16*j);
      fsplit(r[4+j],h,l);
      qh |= (unsigned long long)h << (16*j);  ql |= (unsigned long long)l << (16*j);
    }
    size_t base = (size_t)row * NC + lane*4;
    *(unsigned long long*)(sh + base)       = ph;
    *(unsigned long long*)(sl + base)       = pl;
    *(unsigned long long*)(sh + base + 256) = qh;
    *(unsigned long long*)(sl + base + 256) = ql;
  }
}

// ---------------- split-bf16 MFMA GEMM, both operands K-innermost ----------------
// C(m,n) = sum_k A[m][k]*B[n][k]  (A: M x K ld512, B: N x K ld512)
// EPI 1: relu(acc+bias[n]) -> split bf16 OutH/OutL
// EPI 2: Cf[m][n] = S2[m][n] + scale[n]*acc
template<int EPI>
__global__ void __launch_bounds__(256,2) gemmA_kernel(
    const unsigned short* __restrict__ Ah, const unsigned short* __restrict__ Al,
    const unsigned short* __restrict__ Bh, const unsigned short* __restrict__ Bl,
    unsigned short* __restrict__ OutH, unsigned short* __restrict__ OutL,
    float* __restrict__ Cf, const float* __restrict__ S2,
    const float* __restrict__ bias, const float* __restrict__ scale,
    int K, long sA, long sB, long sC)
{
  __shared__ __align__(16) unsigned char smem[32768];  // Ah:0 Al:8K Bh:16K Bl:24K
  int bz = blockIdx.z;
  Ah += (size_t)bz*sA; Al += (size_t)bz*sA;
  Bh += (size_t)bz*sB; Bl += (size_t)bz*sB;
  if constexpr (EPI==2){ Cf += (size_t)bz*sC; S2 += (size_t)bz*sC; scale += (size_t)bz*NC; }
  int m0 = blockIdx.x*128, n0 = blockIdx.y*128;
  int tid = threadIdx.x;
  int l = tid & 63, wid = tid >> 6;
  int wr = wid >> 1, wc = wid & 1;
  int lr = l & 15, lk = l >> 4;

  int offA[4], offB[4];
  #pragma unroll
  for (int i=0;i<4;i++){
    int ra = wr*64 + i*16 + lr;
    offA[i] = ra*64 + ((lk ^ ((ra>>1)&3))<<4);
    int rb = wc*64 + i*16 + lr;
    offB[i] = rb*64 + ((lk ^ ((rb>>1)&3))<<4);
  }

  int srow = tid >> 2;                         // 0..63
  int gslot = (tid & 3) ^ ((srow>>1)&3);       // pre-swizzled global k-slot
  unsigned char* ldsw = smem + (tid>>6)*1024;  // wave-uniform base (+tile,+h2*4096)
  const unsigned short* gAh = Ah + (size_t)(m0 + srow)*512 + gslot*8;
  const unsigned short* gAl = Al + (size_t)(m0 + srow)*512 + gslot*8;
  const unsigned short* gBh = Bh + (size_t)(n0 + srow)*512 + gslot*8;
  const unsigned short* gBl = Bl + (size_t)(n0 + srow)*512 + gslot*8;
  const size_t rstep = (size_t)64*512;

  f32x4 acc[4][4] = {};

  for (int k0 = 0; k0 < K; k0 += 32){
    __syncthreads();
    gload16(gAh + k0,         ldsw);
    gload16(gAh + k0 + rstep, ldsw + 4096);
    gload16(gAl + k0,         ldsw + 8192);
    gload16(gAl + k0 + rstep, ldsw + 12288);
    gload16(gBh + k0,         ldsw + 16384);
    gload16(gBh + k0 + rstep, ldsw + 20480);
    gload16(gBl + k0,         ldsw + 24576);
    gload16(gBl + k0 + rstep, ldsw + 28672);
    __syncthreads();
    short8v ah[4], alo[4], bh[4], blo[4];
    #pragma unroll
    for (int i=0;i<4;i++){
      ah[i]  = *(const short8v*)(smem + offA[i]);
      alo[i] = *(const short8v*)(smem + 8192  + offA[i]);
      bh[i]  = *(const short8v*)(smem + 16384 + offB[i]);
      blo[i] = *(const short8v*)(smem + 24576 + offB[i]);
    }
    #pragma unroll
    for (int i=0;i<4;i++)
      #pragma unroll
      for (int j=0;j<4;j++) acc[i][j] = MFMA16(ah[i], bh[j], acc[i][j]);
    #pragma unroll
    for (int i=0;i<4;i++)
      #pragma unroll
      for (int j=0;j<4;j++) acc[i][j] = MFMA16(ah[i], blo[j], acc[i][j]);
    #pragma unroll
    for (int i=0;i<4;i++)
      #pragma unroll
      for (int j=0;j<4;j++) acc[i][j] = MFMA16(alo[i], bh[j], acc[i][j]);
  }

  #pragma unroll
  for (int j=0;j<4;j++){
    int gcol = n0 + wc*64 + j*16 + lr;
    float bv = 0.f, scv = 0.f;
    if constexpr (EPI==1) bv = bias[gcol];
    if constexpr (EPI==2) scv = scale[gcol];
    #pragma unroll
    for (int i=0;i<4;i++){
      #pragma unroll
      for (int r=0;r<4;r++){
        int grow = m0 + wr*64 + i*16 + lk*4 + r;
        size_t idx = (size_t)grow*512 + gcol;
        float v = acc[i][j][r];
        if constexpr (EPI==1){
          v = fmaxf(v + bv, 0.f);
          unsigned short h,lo2; fsplit(v,h,lo2);
          OutH[idx]=h; OutL[idx]=lo2;
        } else {
          Cf[idx] = S2[idx] + scv*v;
        }
      }
    }
  }
}

// ---------------- GEMM2: xn[c][h] = sum_n st[n][c] z[n][h]  (transposed staging) ----------------
__global__ void __launch_bounds__(256,2) gemmT_kernel(
    const unsigned short* __restrict__ Ah, const unsigned short* __restrict__ Al,
    const unsigned short* __restrict__ Bh, const unsigned short* __restrict__ Bl,
    unsigned short* __restrict__ OutH, unsigned short* __restrict__ OutL,
    float* __restrict__ parts, int K)
{
  __shared__ __align__(16) unsigned char smem[32768];
  int bz = blockIdx.z;
  size_t boff = (size_t)bz * NN * 512;
  Ah += boff; Al += boff; Bh += boff; Bl += boff;
  int m0 = blockIdx.x*128, n0 = blockIdx.y*128;
  int tid = threadIdx.x;
  int l = tid & 63, wid = tid >> 6;
  int wr = wid >> 1, wc = wid & 1;
  int lr = l & 15, lk = l >> 4;

  int offA[4], offB[4];
  #pragma unroll
  for (int i=0;i<4;i++){
    int ra = wr*64 + i*16 + lr;
    offA[i] = ra*64 + ((lk ^ ((ra>>1)&3))<<4);
    int rb = wc*64 + i*16 + lr;
    offB[i] = rb*64 + ((lk ^ ((rb>>1)&3))<<4);
  }

  int nl2 = (tid & 15)*2;      // even k-row pair within tile
  int cg  = tid >> 4;          // 0..15 : 8-col group
  int sl  = nl2 >> 3;
  int innb = (nl2 & 7)*2;      // byte within 16B slot

  f32x4 acc[4][4] = {};

  for (int k0 = 0; k0 < K; k0 += 32){
    // global loads (before barrier: overlap prior compute/barrier wait)
    size_t g0 = (size_t)(k0 + nl2)*512 + cg*8;
    short8v va0 = *(const short8v*)(Ah + g0 + m0);
    short8v va1 = *(const short8v*)(Ah + g0 + m0 + 512);
    short8v wa0 = *(const short8v*)(Al + g0 + m0);
    short8v wa1 = *(const short8v*)(Al + g0 + m0 + 512);
    short8v vb0 = *(const short8v*)(Bh + g0 + n0);
    short8v vb1 = *(const short8v*)(Bh + g0 + n0 + 512);
    short8v wb0 = *(const short8v*)(Bl + g0 + n0);
    short8v wb1 = *(const short8v*)(Bl + g0 + n0 + 512);
    __syncthreads();
    #pragma unroll
    for (int j=0;j<8;j++){
      int c = cg*8 + j;
      int byo = c*64 + ((sl ^ ((c>>1)&3))<<4) + innb;
      *(unsigned int*)(smem + byo)         = (unsigned int)(unsigned short)va0[j] | ((unsigned int)(unsigned short)va1[j]<<16);
      *(unsigned int*)(smem + 8192 + byo)  = (unsigned int)(unsigned short)wa0[j] | ((unsigned int)(unsigned short)wa1[j]<<16);
      *(unsigned int*)(smem + 16384 + byo) = (unsigned int)(unsigned short)vb0[j] | ((unsigned int)(unsigned short)vb1[j]<<16);
      *(unsigned int*)(smem + 24576 + byo) = (unsigned int)(unsigned short)wb0[j] | ((unsigned int)(unsigned short)wb1[j]<<16);
    }
    __syncthreads();
    short8v ah[4], alo[4], bh[4], blo[4];
    #pragma unroll
    for (int i=0;i<4;i++){
      ah[i]  = *(const short8v*)(smem + offA[i]);
      alo[i] = *(const short8v*)(smem + 8192  + offA[i]);
      bh[i]  = *(const short8v*)(smem + 16384 + offB[i]);
      blo[i] = *(const short8v*)(smem + 24576 + offB[i]);
    }
    #pragma unroll
    for (int i=0;i<4;i++)
      #pragma unroll
      for (int j=0;j<4;j++) acc[i][j] = MFMA16(ah[i], bh[j], acc[i][j]);
    #pragma unroll
    for (int i=0;i<4;i++)
      #pragma unroll
      for (int j=0;j<4;j++) acc[i][j] = MFMA16(ah[i], blo[j], acc[i][j]);
    #pragma unroll
    for (int i=0;i<4;i++)
      #pragma unroll
      for (int j=0;j<4;j++) acc[i][j] = MFMA16(alo[i], bh[j], acc[i][j]);
  }

  // epilogue: split store + per-row (c) sum of squares partials
  #pragma unroll
  for (int i=0;i<4;i++){
    #pragma unroll
    for (int r=0;r<4;r++){
      int grow = m0 + wr*64 + i*16 + lk*4 + r;
      float p = 0.f;
      #pragma unroll
      for (int j=0;j<4;j++){
        float v = acc[i][j][r];
        p = fmaf(v,v,p);
        int gcol = n0 + wc*64 + j*16 + lr;
        size_t idx = (size_t)bz*NC*NH + (size_t)grow*512 + gcol;
        unsigned short h,lo2; fsplit(v,h,lo2);
        OutH[idx]=h; OutL[idx]=lo2;
      }
      p += __shfl_xor(p, 1, 64);
      p += __shfl_xor(p, 2, 64);
      p += __shfl_xor(p, 4, 64);
      p += __shfl_xor(p, 8, 64);
      if (lr == 0) parts[(((size_t)bz*NC) + grow)*8 + blockIdx.y*2 + wc] = p;
    }
  }
}

// ---------------- squash scale from partials ----------------
__global__ void __launch_bounds__(512) scale_kernel(const float* __restrict__ parts,
                                                    float* __restrict__ scale){
  int b = blockIdx.x, c = threadIdx.x;
  const float* p = parts + ((size_t)b*NC + c)*8;
  float m2 = ((p[0]+p[1])+(p[2]+p[3])) + ((p[4]+p[5])+(p[6]+p[7]));
  float sc = 0.0f;
  if (m2 > 0.0f) sc = (m2/(1.0f+m2)) / sqrtf(m2);
  scale[(size_t)b*NC + c] = sc;
}

// ---------------- orchestration ----------------
extern "C" void kernel_launch(void* const* d_in, const int* in_sizes, int n_in,
                              void* d_out, int out_size, void* d_ws, size_t ws_size,
                              hipStream_t stream) {
  const float* x    = (const float*)d_in[0];
  const float* adj  = (const float*)d_in[1];
  const float* W    = (const float*)d_in[2];
  const float* bias = (const float*)d_in[3];
  const unsigned char* mask = (const unsigned char*)d_in[4];
  float* out = (float*)d_out;                 // holds s (f32) and finally softmax(s)
  char* ws = (char*)d_ws;

  unsigned short* zh   = (unsigned short*)(ws);                 // 64 MB
  unsigned short* zl   = zh + (size_t)ROWS*NH;                  // 64 MB
  unsigned short* sth  = (unsigned short*)(ws + 134217728);     // 64 MB (aliases yh)
  unsigned short* stl  = sth + (size_t)ROWS*NC;                 // 64 MB (aliases yl)
  unsigned short* xnh  = (unsigned short*)(ws + 268435456);     // 16 MB
  unsigned short* xnl  = xnh + (size_t)NB*NC*NH;                // 16 MB
  unsigned short* WTh  = (unsigned short*)(ws + 301989888);     // 0.5 MB
  unsigned short* WTl  = WTh + 512*512;                         // 0.5 MB
  float* parts         = (float*)(ws + 303038464);              // 0.5 MB
  float* scalebuf      = (float*)(ws + 303562752);              // 64 KB
  int*   cnum          = (int*)(ws + 303628288);
  unsigned short* yh = sth;
  unsigned short* yl = stl;

  counts_kernel<<<NB, 256, 0, stream>>>(mask, cnum);
  wsplit_kernel<<<dim3(16,16), 256, 0, stream>>>(W, WTh, WTl);
  spmm_kernel<<<ROWS, 256, 0, stream>>>(adj, x, yh, yl);
  // z = relu(y @ W + b): M=65536 N=512 K=512
  gemmA_kernel<1><<<dim3(512,4,1), 256, 0, stream>>>(
      yh, yl, WTh, WTl, zh, zl, nullptr, nullptr, bias, nullptr, ND, 0, 0, 0);
  // s0 = jax.random.normal(key(42)) -> d_out
  rng_kernel<<<(ROWS*NC)/256, 256, 0, stream>>>(out);

  for (int it = 0; it < 3; ++it){
    // s~ = masked_softmax(s): f32 in-place in d_out, plus split bf16 copies
    softmax_kernel<true><<<ROWS/4, 256, 0, stream>>>(out, sth, stl, cnum);
    // xn[c][h] = sum_n s~[n][c] z[n][h]  (+ row sumsq partials)
    gemmT_kernel<<<dim3(4,4,NB), 256, 0, stream>>>(
        sth, stl, zh, zl, xnh, xnl, parts, NN);
    scale_kernel<<<NB, 512, 0, stream>>>(parts, scalebuf);
    // s = s~ + scale[c] * (z @ xn^T): M=2048 N=512 K=512 per batch
    gemmA_kernel<2><<<dim3(16,4,NB), 256, 0, stream>>>(
        zh, zl, xnh, xnl, nullptr, nullptr, out, out, nullptr, scalebuf,
        NH, (long)NN*NH, (long)NC*NH, (long)NN*NC);
  }
  softmax_kernel<false><<<ROWS/4, 256, 0, stream>>>(out, nullptr, nullptr, cnum);
}

// Round 4
// 1484.613 us; speedup vs baseline: 2.1700x; 1.1740x over previous
//
#include <hip/hip_runtime.h>
#include <cstdint>
#include <cstddef>

#define NB 32
#define NN 2048
#define ND 512
#define NH 512
#define NC 512
#define ROWS (NB*NN)                 // 65536

typedef __attribute__((ext_vector_type(8))) short short8v;   // 8 bf16 (4 VGPR)
typedef __attribute__((ext_vector_type(4))) float f32x4;

#define MFMA16(a,b,c) __builtin_amdgcn_mfma_f32_16x16x32_bf16((a),(b),(c),0,0,0)

typedef const __attribute__((address_space(1))) unsigned int* gas_t;
typedef __attribute__((address_space(3))) unsigned int* las_t;

__device__ __forceinline__ void gload16(const void* g, void* l){
  __builtin_amdgcn_global_load_lds((gas_t)g, (las_t)l, 16, 0, 0);
}

// f32 -> bf16 hi/lo split (RNE both).  v ~= h + l, |v-h-l| <= 2^-18 |v|
__device__ __forceinline__ void fsplit(float v, unsigned short& h, unsigned short& l){
  unsigned u = __float_as_uint(v);
  unsigned hb = (u + 0x7FFFu + ((u>>16)&1u)) >> 16;
  float hf = __uint_as_float(hb<<16);
  float r = v - hf;
  unsigned ur = __float_as_uint(r);
  l = (unsigned short)((ur + 0x7FFFu + ((ur>>16)&1u)) >> 16);
  h = (unsigned short)hb;
}

// ---------------- threefry2x32-20 (JAX partitionable scheme) ----------------
__device__ __forceinline__ unsigned rotl32(unsigned x, int d){ return (x<<d)|(x>>(32-d)); }

__device__ __forceinline__ unsigned threefry_xor(unsigned k0, unsigned k1, unsigned c0, unsigned c1){
  unsigned ks2 = 0x1BD11BDAu ^ k0 ^ k1;
  unsigned x0 = c0 + k0, x1 = c1 + k1;
#define TF_RND(r) { x0 += x1; x1 = rotl32(x1,(r)); x1 ^= x0; }
  TF_RND(13) TF_RND(15) TF_RND(26) TF_RND(6)
  x0 += k1;  x1 += ks2 + 1u;
  TF_RND(17) TF_RND(29) TF_RND(16) TF_RND(24)
  x0 += ks2; x1 += k0 + 2u;
  TF_RND(13) TF_RND(15) TF_RND(26) TF_RND(6)
  x0 += k0;  x1 += k1 + 3u;
  TF_RND(17) TF_RND(29) TF_RND(16) TF_RND(24)
  x0 += k1;  x1 += ks2 + 4u;
  TF_RND(13) TF_RND(15) TF_RND(26) TF_RND(6)
  x0 += ks2; x1 += k0 + 5u;
#undef TF_RND
  return x0 ^ x1;
}

__device__ __forceinline__ float bits_to_normal(unsigned bits){
  float f = __uint_as_float((bits >> 9) | 0x3f800000u) - 1.0f;
  const float lo = -0.99999994f;
  float u = fmaxf(lo, fmaf(f, 2.0f, lo));
  float w = -log1pf(-(u*u));
  float p;
  if (w < 5.0f){
    w -= 2.5f;
    p =            2.81022636e-08f;
    p = fmaf(p, w, 3.43273939e-07f);
    p = fmaf(p, w, -3.5233877e-06f);
    p = fmaf(p, w, -4.39150654e-06f);
    p = fmaf(p, w, 0.00021858087f);
    p = fmaf(p, w, -0.00125372503f);
    p = fmaf(p, w, -0.00417768164f);
    p = fmaf(p, w, 0.246640727f);
    p = fmaf(p, w, 1.50140941f);
  } else {
    w = sqrtf(w) - 3.0f;
    p =            -0.000200214257f;
    p = fmaf(p, w, 0.000100950558f);
    p = fmaf(p, w, 0.00134934322f);
    p = fmaf(p, w, -0.00367342844f);
    p = fmaf(p, w, 0.00573950773f);
    p = fmaf(p, w, -0.0076224613f);
    p = fmaf(p, w, 0.00943887047f);
    p = fmaf(p, w, 1.00167406f);
    p = fmaf(p, w, 2.83297682f);
  }
  return 1.4142135623730951f * (p * u);
}

__global__ void __launch_bounds__(256) rng_kernel(float* __restrict__ s){
  unsigned i = blockIdx.x * 256u + threadIdx.x;
  s[i] = bits_to_normal(threefry_xor(0u, 42u, 0u, i));
}

// ---------------- cluster counts ----------------
__global__ void __launch_bounds__(256) counts_kernel(const unsigned char* __restrict__ mraw,
                                                     int* __restrict__ cnum){
  __shared__ int red[256];
  int b = blockIdx.x, tid = threadIdx.x;
  unsigned char b0 = mraw[0], b1 = mraw[1];
  int cnt = 0;
  if (b0 == 1 && b1 == 1){
    const unsigned char* p = mraw + (size_t)b * NN;
    for (int i = tid; i < NN; i += 256) cnt += (p[i] != 0);
  } else if (b0 == 1){
    const int* p = (const int*)mraw + (size_t)b * NN;
    for (int i = tid; i < NN; i += 256) cnt += (p[i] != 0);
  } else {
    const float* p = (const float*)mraw + (size_t)b * NN;
    for (int i = tid; i < NN; i += 256) cnt += (p[i] != 0.0f);
  }
  red[tid] = cnt; __syncthreads();
  for (int off = 128; off; off >>= 1){ if (tid < off) red[tid] += red[tid+off]; __syncthreads(); }
  if (tid == 0) cnum[b] = red[0] >> 2;
}

// ---------------- y = adj @ x, writes split bf16 ----------------
__global__ void __launch_bounds__(256) spmm_kernel(const float* __restrict__ adj,
                                                   const float* __restrict__ x,
                                                   unsigned short* __restrict__ yh,
                                                   unsigned short* __restrict__ yl){
  __shared__ int   idxs[NN];
  __shared__ float vals[NN];
  __shared__ int   scan[256];
  int row = blockIdx.x;
  int b = row >> 11;
  int tid = threadIdx.x;
  const float* arow = adj + (size_t)row * NN;
  float v[8];
  *(float4*)&v[0] = *(const float4*)(arow + tid*8);
  *(float4*)&v[4] = *(const float4*)(arow + tid*8 + 4);
  int lc = 0;
  #pragma unroll
  for (int j=0;j<8;j++) lc += (v[j] != 0.0f);
  scan[tid] = lc; __syncthreads();
  for (int off=1; off<256; off<<=1){
    int t = (tid >= off) ? scan[tid-off] : 0;
    __syncthreads();
    scan[tid] += t;
    __syncthreads();
  }
  int pos = scan[tid] - lc;
  int total = scan[255];
  #pragma unroll
  for (int j=0;j<8;j++){
    if (v[j] != 0.0f){ idxs[pos] = tid*8 + j; vals[pos] = v[j]; pos++; }
  }
  __syncthreads();
  float acc0 = 0.f, acc1 = 0.f;
  const float* xb = x + (size_t)b * NN * ND;
  for (int j=0;j<total;j++){
    int m = idxs[j]; float a = vals[j];
    acc0 = fmaf(a, xb[(size_t)m*ND + tid      ], acc0);
    acc1 = fmaf(a, xb[(size_t)m*ND + tid + 256], acc1);
  }
  unsigned short h,l;
  size_t base = (size_t)row * ND;
  fsplit(acc0,h,l); yh[base+tid]=h;     yl[base+tid]=l;
  fsplit(acc1,h,l); yh[base+tid+256]=h; yl[base+tid+256]=l;
}

// ---------------- W transpose + split: WT[h][d] ----------------
__global__ void __launch_bounds__(256) wsplit_kernel(const float* __restrict__ W,
                                                     unsigned short* __restrict__ WTh,
                                                     unsigned short* __restrict__ WTl){
  __shared__ float t[32][33];
  int bx = blockIdx.x, by = blockIdx.y;
  int x = threadIdx.x & 31, y = threadIdx.x >> 5;
  for (int yy=y; yy<32; yy+=8) t[yy][x] = W[(size_t)(bx*32+yy)*512 + by*32 + x];
  __syncthreads();
  for (int yy=y; yy<32; yy+=8){
    float v = t[x][yy];                     // = W[bx*32+x][by*32+yy]
    unsigned short h,l; fsplit(v,h,l);
    size_t idx = (size_t)(by*32+yy)*512 + bx*32 + x;
    WTh[idx]=h; WTl[idx]=l;
  }
}

// ---------------- masked softmax (in-place f32 + optional split out) ----------------
template<bool SPLIT>
__global__ void __launch_bounds__(256) softmax_kernel(float* __restrict__ s,
                                                      unsigned short* __restrict__ sh,
                                                      unsigned short* __restrict__ sl,
                                                      const int* __restrict__ cnum){
  int row  = blockIdx.x*4 + (threadIdx.x >> 6);
  int lane = threadIdx.x & 63;
  int b = row >> 11;
  int Kc = cnum[b];
  float* p = s + (size_t)row * NC;
  float4 v0 = *(const float4*)(p + lane*4);
  float4 v1 = *(const float4*)(p + lane*4 + 256);
  float e[8] = {v0.x,v0.y,v0.z,v0.w,v1.x,v1.y,v1.z,v1.w};
  float m = -3.0e38f;
  #pragma unroll
  for (int j=0;j<8;j++){
    int c = (j<4) ? lane*4 + j : lane*4 + 252 + j;
    if (c < Kc) m = fmaxf(m, e[j]);
  }
  #pragma unroll
  for (int off=32; off; off>>=1) m = fmaxf(m, __shfl_xor(m, off, 64));
  float r[8]; float sum = 0.f;
  #pragma unroll
  for (int j=0;j<8;j++){
    int c = (j<4) ? lane*4 + j : lane*4 + 252 + j;
    r[j] = (c < Kc) ? expf(e[j] - m) : 0.0f;
    sum += r[j];
  }
  #pragma unroll
  for (int off=32; off; off>>=1) sum += __shfl_xor(sum, off, 64);
  float inv = 1.0f / sum;
  #pragma unroll
  for (int j=0;j<8;j++) r[j] *= inv;
  *(float4*)(p + lane*4)       = make_float4(r[0],r[1],r[2],r[3]);
  *(float4*)(p + lane*4 + 256) = make_float4(r[4],r[5],r[6],r[7]);
  if constexpr (SPLIT){
    unsigned long long ph=0, pl=0, qh=0, ql=0;
    #pragma unroll
    for (int j=0;j<4;j++){
      unsigned short h,l;
      fsplit(r[j],h,l);
      ph |= (unsigned long long)h << (16*j);  pl |= (unsigned long long)l << (16*j);
      fsplit(r[4+j],h,l);
      qh |= (unsigned long long)h << (16*j);  ql |= (unsigned long long)l << (16*j);
    }
    size_t base = (size_t)row * NC + lane*4;
    *(unsigned long long*)(sh + base)       = ph;
    *(unsigned long long*)(sl + base)       = pl;
    *(unsigned long long*)(sh + base + 256) = qh;
    *(unsigned long long*)(sl + base + 256) = ql;
  }
}

// ============ 256x256 8-wave split-bf16 GEMM, K-innermost operands ============
// C(m,n) = sum_k A[m][k]*B[n][k]   A: M x 512, B: N x 512 (both h+l planes)
// EPI 1: relu(acc+bias[n]) -> split OutH/OutL.   EPI 2: Cf = S2 + scale[n]*acc
// 8 waves: wr = wid>>2 (128-row half), wc = wid&3 (64-col strip).
template<int EPI>
__global__ void __launch_bounds__(512,2) gemm256_kernel(
    const unsigned short* __restrict__ Ah, const unsigned short* __restrict__ Al,
    const unsigned short* __restrict__ Bh, const unsigned short* __restrict__ Bl,
    unsigned short* __restrict__ OutH, unsigned short* __restrict__ OutL,
    float* __restrict__ Cf, const float* __restrict__ S2,
    const float* __restrict__ bias, const float* __restrict__ scale,
    int K, long sA, long sB, long sC)
{
  __shared__ __align__(16) unsigned char smem[131072];   // 2 x 64KB buffers
  int bz = blockIdx.z;
  Ah += (size_t)bz*sA; Al += (size_t)bz*sA;
  Bh += (size_t)bz*sB; Bl += (size_t)bz*sB;
  if constexpr (EPI==2){ Cf += (size_t)bz*sC; S2 += (size_t)bz*sC; scale += (size_t)bz*NC; }
  int m0 = blockIdx.x*256, n0 = blockIdx.y*256;
  int tid = threadIdx.x;
  int l = tid & 63, wid = tid >> 6;
  int wr = wid >> 2, wc = wid & 3;
  int lr = l & 15, lk = l >> 4;

  // fragment read offsets within a 16KB matrix region
  int offA[8], offB[4];
  #pragma unroll
  for (int i=0;i<8;i++){
    int ra = wr*128 + i*16 + lr;
    offA[i] = ra*64 + ((lk ^ ((ra>>1)&3))<<4);
  }
  #pragma unroll
  for (int j=0;j<4;j++){
    int rb = wc*64 + j*16 + lr;
    offB[j] = rb*64 + ((lk ^ ((rb>>1)&3))<<4);
  }

  // staging: per matrix 256rows x 64B = 16KB = 2 issues of (512thr x 16B)
  int srow = tid >> 2;                          // 0..127
  int gslot = (tid & 3) ^ ((srow>>1)&3);        // pre-swizzled global k-slot
  const unsigned short* gA0 = Ah + (size_t)(m0 +       srow)*512 + gslot*8;
  const unsigned short* gA1 = Ah + (size_t)(m0 + 128 + srow)*512 + gslot*8;
  const unsigned short* gA2 = Al + (size_t)(m0 +       srow)*512 + gslot*8;
  const unsigned short* gA3 = Al + (size_t)(m0 + 128 + srow)*512 + gslot*8;
  const unsigned short* gB0 = Bh + (size_t)(n0 +       srow)*512 + gslot*8;
  const unsigned short* gB1 = Bh + (size_t)(n0 + 128 + srow)*512 + gslot*8;
  const unsigned short* gB2 = Bl + (size_t)(n0 +       srow)*512 + gslot*8;
  const unsigned short* gB3 = Bl + (size_t)(n0 + 128 + srow)*512 + gslot*8;

  f32x4 acc[8][4] = {};

#define STAGE256(buf, k0) { \
    unsigned char* db = smem + (buf)*65536 + wid*1024; \
    gload16(gA0 + (k0), db);          gload16(gA1 + (k0), db + 8192); \
    gload16(gA2 + (k0), db + 16384);  gload16(gA3 + (k0), db + 24576); \
    gload16(gB0 + (k0), db + 32768);  gload16(gB1 + (k0), db + 40960); \
    gload16(gB2 + (k0), db + 49152);  gload16(gB3 + (k0), db + 57344); }

  STAGE256(0, 0)
  __syncthreads();
  int KT = K >> 5;
  for (int t = 0; t < KT; ++t){
    if (t+1 < KT) STAGE256((t+1)&1, (t+1)*32)
    const unsigned char* base = smem + (t&1)*65536;
    short8v ah[8], bh[4], bl[4];
    #pragma unroll
    for (int i=0;i<8;i++) ah[i] = *(const short8v*)(base + offA[i]);
    #pragma unroll
    for (int j=0;j<4;j++){
      bh[j] = *(const short8v*)(base + 32768 + offB[j]);
      bl[j] = *(const short8v*)(base + 49152 + offB[j]);
    }
    #pragma unroll
    for (int i=0;i<8;i++)
      #pragma unroll
      for (int j=0;j<4;j++) acc[i][j] = MFMA16(ah[i], bh[j], acc[i][j]);
    #pragma unroll
    for (int i=0;i<8;i++)
      #pragma unroll
      for (int j=0;j<4;j++) acc[i][j] = MFMA16(ah[i], bl[j], acc[i][j]);
    #pragma unroll
    for (int i=0;i<8;i++){
      short8v al = *(const short8v*)(base + 16384 + offA[i]);
      #pragma unroll
      for (int j=0;j<4;j++) acc[i][j] = MFMA16(al, bh[j], acc[i][j]);
    }
    __syncthreads();
  }
#undef STAGE256

  // epilogue
  float aux[4];
  #pragma unroll
  for (int j=0;j<4;j++){
    int gcol = n0 + wc*64 + j*16 + lr;
    if constexpr (EPI==1) aux[j] = bias[gcol];
    if constexpr (EPI==2) aux[j] = scale[gcol];
  }
  #pragma unroll
  for (int i=0;i<8;i++){
    #pragma unroll
    for (int r=0;r<4;r++){
      int grow = m0 + wr*128 + i*16 + lk*4 + r;
      size_t rowb = (size_t)grow*512 + n0 + wc*64 + lr;
      #pragma unroll
      for (int j=0;j<4;j++){
        float v = acc[i][j][r];
        if constexpr (EPI==1){
          v = fmaxf(v + aux[j], 0.f);
          unsigned short h,lo2; fsplit(v,h,lo2);
          OutH[rowb + j*16] = h; OutL[rowb + j*16] = lo2;
        } else {
          Cf[rowb + j*16] = S2[rowb + j*16] + aux[j]*v;
        }
      }
    }
  }
}

// ============ GEMM2: xn[c][h] = sum_n st[n][c] z[n][h], 256x128 tile ============
// reg-staged transposed staging (T14 split). partials for squash.
__global__ void __launch_bounds__(512,2) gemmT256_kernel(
    const unsigned short* __restrict__ Ah, const unsigned short* __restrict__ Al,
    const unsigned short* __restrict__ Bh, const unsigned short* __restrict__ Bl,
    unsigned short* __restrict__ OutH, unsigned short* __restrict__ OutL,
    float* __restrict__ parts, int K)
{
  __shared__ __align__(16) unsigned char smem[98304];   // 2 x 48KB (A:16+16, B:8+8)
  int bz = blockIdx.z;
  size_t boff = (size_t)bz * NN * 512;
  Ah += boff; Al += boff; Bh += boff; Bl += boff;
  int m0 = blockIdx.x*256, n0 = blockIdx.y*128;
  int tid = threadIdx.x;
  int l = tid & 63, wid = tid >> 6;
  int wr = wid >> 2, wc = wid & 3;          // wr: 128-c half, wc: 32-h strip
  int lr = l & 15, lk = l >> 4;

  int offA[8], offB[2];
  #pragma unroll
  for (int i=0;i<8;i++){
    int ra = wr*128 + i*16 + lr;
    offA[i] = ra*64 + ((lk ^ ((ra>>1)&3) ^ ((ra>>3)&3))<<4);
  }
  #pragma unroll
  for (int j=0;j<2;j++){
    int rb = wc*32 + j*16 + lr;
    offB[j] = rb*64 + ((lk ^ ((rb>>1)&3) ^ ((rb>>3)&3))<<4);
  }

  // A-stage map: all 512 thr: npair=tid&15 (n = 2*npair), cseg=tid>>4 (c = cseg*8)
  // B-stage map: tid<256: npair=tid&15, hseg=tid>>4 (h = hseg*8)
  int np  = tid & 15;
  int seg = tid >> 4;          // 0..31 for A; 0..15 for B (tid<256)
  f32x4 acc[8][2] = {};

  short8v ra0h, ra1h, ra0l, ra1l, rb0h, rb1h, rb0l, rb1l;
  int have_b = (tid < 256);

#define TLOAD(k0) { \
    size_t ga = (size_t)((k0) + 2*np)*512 + m0 + seg*8; \
    ra0h = *(const short8v*)(Ah + ga); ra1h = *(const short8v*)(Ah + ga + 512); \
    ra0l = *(const short8v*)(Al + ga); ra1l = *(const short8v*)(Al + ga + 512); \
    if (have_b){ \
      size_t gb = (size_t)((k0) + 2*np)*512 + n0 + seg*8; \
      rb0h = *(const short8v*)(Bh + gb); rb1h = *(const short8v*)(Bh + gb + 512); \
      rb0l = *(const short8v*)(Bl + gb); rb1l = *(const short8v*)(Bl + gb + 512); } }

#define TWRITE(buf) { \
    unsigned char* bb = smem + (buf)*49152; \
    _Pragma("unroll") \
    for (int k=0;k<8;k++){ \
      int c = seg*8 + k; \
      int ps = (np>>2) ^ ((c>>1)&3) ^ ((c>>3)&3); \
      int byo = c*64 + ps*16 + (np&3)*4; \
      *(unsigned int*)(bb + byo)         = (unsigned int)(unsigned short)ra0h[k] | ((unsigned int)(unsigned short)ra1h[k]<<16); \
      *(unsigned int*)(bb + 16384 + byo) = (unsigned int)(unsigned short)ra0l[k] | ((unsigned int)(unsigned short)ra1l[k]<<16); \
      if (have_b){ \
        *(unsigned int*)(bb + 32768 + byo) = (unsigned int)(unsigned short)rb0h[k] | ((unsigned int)(unsigned short)rb1h[k]<<16); \
        *(unsigned int*)(bb + 40960 + byo) = (unsigned int)(unsigned short)rb0l[k] | ((unsigned int)(unsigned short)rb1l[k]<<16); } } }

  TLOAD(0)
  TWRITE(0)
  __syncthreads();
  int KT = K >> 5;
  for (int t = 0; t < KT; ++t){
    int more = (t+1 < KT);
    if (more) TLOAD((t+1)*32)
    const unsigned char* base = smem + (t&1)*49152;
    short8v ah[8], bh[2], bl[2];
    #pragma unroll
    for (int i=0;i<8;i++) ah[i] = *(const short8v*)(base + offA[i]);
    #pragma unroll
    for (int j=0;j<2;j++){
      bh[j] = *(const short8v*)(base + 32768 + offB[j]);
      bl[j] = *(const short8v*)(base + 40960 + offB[j]);
    }
    #pragma unroll
    for (int i=0;i<8;i++)
      #pragma unroll
      for (int j=0;j<2;j++) acc[i][j] = MFMA16(ah[i], bh[j], acc[i][j]);
    #pragma unroll
    for (int i=0;i<8;i++)
      #pragma unroll
      for (int j=0;j<2;j++) acc[i][j] = MFMA16(ah[i], bl[j], acc[i][j]);
    #pragma unroll
    for (int i=0;i<8;i++){
      short8v al = *(const short8v*)(base + 16384 + offA[i]);
      #pragma unroll
      for (int j=0;j<2;j++) acc[i][j] = MFMA16(al, bh[j], acc[i][j]);
    }
    if (more) TWRITE((t+1)&1)
    __syncthreads();
  }
#undef TLOAD
#undef TWRITE

  // epilogue: split store + per-c-row sum-of-squares partials
  #pragma unroll
  for (int i=0;i<8;i++){
    #pragma unroll
    for (int r=0;r<4;r++){
      int grow = m0 + wr*128 + i*16 + lk*4 + r;     // c index
      float p = 0.f;
      size_t rowb = (size_t)bz*NC*NH + (size_t)grow*512 + n0 + wc*32 + lr;
      #pragma unroll
      for (int j=0;j<2;j++){
        float v = acc[i][j][r];
        p = fmaf(v,v,p);
        unsigned short h,lo2; fsplit(v,h,lo2);
        OutH[rowb + j*16] = h; OutL[rowb + j*16] = lo2;
      }
      p += __shfl_xor(p, 1, 64);
      p += __shfl_xor(p, 2, 64);
      p += __shfl_xor(p, 4, 64);
      p += __shfl_xor(p, 8, 64);
      if (lr == 0) parts[(((size_t)bz*NC) + grow)*16 + blockIdx.y*4 + wc] = p;
    }
  }
}

// ---------------- squash scale from partials ----------------
__global__ void __launch_bounds__(512) scale_kernel(const float* __restrict__ parts,
                                                    float* __restrict__ scale){
  int b = blockIdx.x, c = threadIdx.x;
  const float* p = parts + ((size_t)b*NC + c)*16;
  float m2 = 0.f;
  #pragma unroll
  for (int j=0;j<16;j++) m2 += p[j];
  float sc = 0.0f;
  if (m2 > 0.0f) sc = (m2/(1.0f+m2)) / sqrtf(m2);
  scale[(size_t)b*NC + c] = sc;
}

// ---------------- orchestration ----------------
extern "C" void kernel_launch(void* const* d_in, const int* in_sizes, int n_in,
                              void* d_out, int out_size, void* d_ws, size_t ws_size,
                              hipStream_t stream) {
  const float* x    = (const float*)d_in[0];
  const float* adj  = (const float*)d_in[1];
  const float* W    = (const float*)d_in[2];
  const float* bias = (const float*)d_in[3];
  const unsigned char* mask = (const unsigned char*)d_in[4];
  float* out = (float*)d_out;                 // holds s (f32) and finally softmax(s)
  char* ws = (char*)d_ws;

  unsigned short* zh   = (unsigned short*)(ws);                 // 64 MB
  unsigned short* zl   = (unsigned short*)(ws + 67108864);      // 64 MB
  unsigned short* sth  = (unsigned short*)(ws + 134217728);     // 64 MB (aliases yh)
  unsigned short* stl  = (unsigned short*)(ws + 201326592);     // 64 MB (aliases yl)
  unsigned short* xnh  = (unsigned short*)(ws + 268435456);     // 16 MB
  unsigned short* xnl  = (unsigned short*)(ws + 285212672);     // 16 MB
  unsigned short* WTh  = (unsigned short*)(ws + 301989888);     // 0.5 MB
  unsigned short* WTl  = (unsigned short*)(ws + 302514176);     // 0.5 MB
  float* parts         = (float*)(ws + 303038464);              // 1 MB
  float* scalebuf      = (float*)(ws + 304087040);              // 64 KB
  int*   cnum          = (int*)(ws + 304152576);
  unsigned short* yh = sth;
  unsigned short* yl = stl;

  counts_kernel<<<NB, 256, 0, stream>>>(mask, cnum);
  wsplit_kernel<<<dim3(16,16), 256, 0, stream>>>(W, WTh, WTl);
  spmm_kernel<<<ROWS, 256, 0, stream>>>(adj, x, yh, yl);
  // z = relu(y @ W + b): M=65536 N=512 K=512
  gemm256_kernel<1><<<dim3(256,2,1), 512, 0, stream>>>(
      yh, yl, WTh, WTl, zh, zl, nullptr, nullptr, bias, nullptr, ND, 0, 0, 0);
  // s0 = jax.random.normal(key(42)) -> d_out
  rng_kernel<<<(ROWS*NC)/256, 256, 0, stream>>>(out);

  for (int it = 0; it < 3; ++it){
    // s~ = masked_softmax(s): f32 in-place in d_out, plus split bf16 copies
    softmax_kernel<true><<<ROWS/4, 256, 0, stream>>>(out, sth, stl, cnum);
    // xn[c][h] = sum_n s~[n][c] z[n][h]  (+ c-row sumsq partials)
    gemmT256_kernel<<<dim3(2,4,NB), 512, 0, stream>>>(
        sth, stl, zh, zl, xnh, xnl, parts, NN);
    scale_kernel<<<NB, 512, 0, stream>>>(parts, scalebuf);
    // s = s~ + scale[c] * (z @ xn^T): M=2048 N=512 K=512 per batch
    gemm256_kernel<2><<<dim3(8,2,NB), 512, 0, stream>>>(
        zh, zl, xnh, xnl, nullptr, nullptr, out, out, nullptr, scalebuf,
        NH, (long)NN*NH, (long)NC*NH, (long)NN*NC);
  }
  softmax_kernel<false><<<ROWS/4, 256, 0, stream>>>(out, nullptr, nullptr, cnum);
}

// Round 5
// 1466.847 us; speedup vs baseline: 2.1963x; 1.0121x over previous
//
#include <hip/hip_runtime.h>
#include <cstdint>
#include <cstddef>

#define NB 32
#define NN 2048
#define ND 512
#define NH 512
#define NC 512
#define ROWS (NB*NN)                 // 65536

typedef __attribute__((ext_vector_type(8))) short short8v;   // 8 bf16 (4 VGPR)
typedef __attribute__((ext_vector_type(4))) float f32x4;

#define MFMA16(a,b,c) __builtin_amdgcn_mfma_f32_16x16x32_bf16((a),(b),(c),0,0,0)

typedef const __attribute__((address_space(1))) unsigned int* gas_t;
typedef __attribute__((address_space(3))) unsigned int* las_t;

__device__ __forceinline__ void gload16(const void* g, void* l){
  __builtin_amdgcn_global_load_lds((gas_t)g, (las_t)l, 16, 0, 0);
}

// f32 -> bf16 hi/lo split (RNE both).  v ~= h + l, |v-h-l| <= 2^-18 |v|
__device__ __forceinline__ void fsplit(float v, unsigned short& h, unsigned short& l){
  unsigned u = __float_as_uint(v);
  unsigned hb = (u + 0x7FFFu + ((u>>16)&1u)) >> 16;
  float hf = __uint_as_float(hb<<16);
  float r = v - hf;
  unsigned ur = __float_as_uint(r);
  l = (unsigned short)((ur + 0x7FFFu + ((ur>>16)&1u)) >> 16);
  h = (unsigned short)hb;
}

// ---------------- threefry2x32-20 (JAX partitionable scheme) ----------------
__device__ __forceinline__ unsigned rotl32(unsigned x, int d){ return (x<<d)|(x>>(32-d)); }

__device__ __forceinline__ unsigned threefry_xor(unsigned k0, unsigned k1, unsigned c0, unsigned c1){
  unsigned ks2 = 0x1BD11BDAu ^ k0 ^ k1;
  unsigned x0 = c0 + k0, x1 = c1 + k1;
#define TF_RND(r) { x0 += x1; x1 = rotl32(x1,(r)); x1 ^= x0; }
  TF_RND(13) TF_RND(15) TF_RND(26) TF_RND(6)
  x0 += k1;  x1 += ks2 + 1u;
  TF_RND(17) TF_RND(29) TF_RND(16) TF_RND(24)
  x0 += ks2; x1 += k0 + 2u;
  TF_RND(13) TF_RND(15) TF_RND(26) TF_RND(6)
  x0 += k0;  x1 += k1 + 3u;
  TF_RND(17) TF_RND(29) TF_RND(16) TF_RND(24)
  x0 += k1;  x1 += ks2 + 4u;
  TF_RND(13) TF_RND(15) TF_RND(26) TF_RND(6)
  x0 += ks2; x1 += k0 + 5u;
#undef TF_RND
  return x0 ^ x1;
}

__device__ __forceinline__ float bits_to_normal(unsigned bits){
  float f = __uint_as_float((bits >> 9) | 0x3f800000u) - 1.0f;
  const float lo = -0.99999994f;
  float u = fmaxf(lo, fmaf(f, 2.0f, lo));
  float w = -log1pf(-(u*u));
  float p;
  if (w < 5.0f){
    w -= 2.5f;
    p =            2.81022636e-08f;
    p = fmaf(p, w, 3.43273939e-07f);
    p = fmaf(p, w, -3.5233877e-06f);
    p = fmaf(p, w, -4.39150654e-06f);
    p = fmaf(p, w, 0.00021858087f);
    p = fmaf(p, w, -0.00125372503f);
    p = fmaf(p, w, -0.00417768164f);
    p = fmaf(p, w, 0.246640727f);
    p = fmaf(p, w, 1.50140941f);
  } else {
    w = sqrtf(w) - 3.0f;
    p =            -0.000200214257f;
    p = fmaf(p, w, 0.000100950558f);
    p = fmaf(p, w, 0.00134934322f);
    p = fmaf(p, w, -0.00367342844f);
    p = fmaf(p, w, 0.00573950773f);
    p = fmaf(p, w, -0.0076224613f);
    p = fmaf(p, w, 0.00943887047f);
    p = fmaf(p, w, 1.00167406f);
    p = fmaf(p, w, 2.83297682f);
  }
  return 1.4142135623730951f * (p * u);
}

__global__ void __launch_bounds__(256) rng_kernel(float* __restrict__ s){
  unsigned i = blockIdx.x * 256u + threadIdx.x;
  s[i] = bits_to_normal(threefry_xor(0u, 42u, 0u, i));
}

// ---------------- cluster counts + lens ----------------
__global__ void __launch_bounds__(256) counts_kernel(const unsigned char* __restrict__ mraw,
                                                     int* __restrict__ cnum,
                                                     int* __restrict__ lenbuf){
  __shared__ int red[256];
  int b = blockIdx.x, tid = threadIdx.x;
  unsigned char b0 = mraw[0], b1 = mraw[1];
  int cnt = 0;
  if (b0 == 1 && b1 == 1){
    const unsigned char* p = mraw + (size_t)b * NN;
    for (int i = tid; i < NN; i += 256) cnt += (p[i] != 0);
  } else if (b0 == 1){
    const int* p = (const int*)mraw + (size_t)b * NN;
    for (int i = tid; i < NN; i += 256) cnt += (p[i] != 0);
  } else {
    const float* p = (const float*)mraw + (size_t)b * NN;
    for (int i = tid; i < NN; i += 256) cnt += (p[i] != 0.0f);
  }
  red[tid] = cnt; __syncthreads();
  for (int off = 128; off; off >>= 1){ if (tid < off) red[tid] += red[tid+off]; __syncthreads(); }
  if (tid == 0){ cnum[b] = red[0] >> 2; lenbuf[b] = red[0]; }
}

// ---------------- y = adj @ x, writes split bf16 (skips dead rows) ----------------
__global__ void __launch_bounds__(256) spmm_kernel(const float* __restrict__ adj,
                                                   const float* __restrict__ x,
                                                   unsigned short* __restrict__ yh,
                                                   unsigned short* __restrict__ yl,
                                                   const int* __restrict__ lenbuf){
  __shared__ int   idxs[NN];
  __shared__ float vals[NN];
  __shared__ int   scan[256];
  int row = blockIdx.x;
  int b = row >> 11;
  int n = row & 2047;
  int tid = threadIdx.x;
  size_t base = (size_t)row * ND;
  if (n >= lenbuf[b]){      // adj row is all-zero: y = 0 (skip 8KB adj read)
    yh[base+tid]=0; yl[base+tid]=0; yh[base+tid+256]=0; yl[base+tid+256]=0;
    return;
  }
  const float* arow = adj + (size_t)row * NN;
  float v[8];
  *(float4*)&v[0] = *(const float4*)(arow + tid*8);
  *(float4*)&v[4] = *(const float4*)(arow + tid*8 + 4);
  int lc = 0;
  #pragma unroll
  for (int j=0;j<8;j++) lc += (v[j] != 0.0f);
  scan[tid] = lc; __syncthreads();
  for (int off=1; off<256; off<<=1){
    int t = (tid >= off) ? scan[tid-off] : 0;
    __syncthreads();
    scan[tid] += t;
    __syncthreads();
  }
  int pos = scan[tid] - lc;
  int total = scan[255];
  #pragma unroll
  for (int j=0;j<8;j++){
    if (v[j] != 0.0f){ idxs[pos] = tid*8 + j; vals[pos] = v[j]; pos++; }
  }
  __syncthreads();
  float acc0 = 0.f, acc1 = 0.f;
  const float* xb = x + (size_t)b * NN * ND;
  for (int j=0;j<total;j++){
    int m = idxs[j]; float a = vals[j];
    acc0 = fmaf(a, xb[(size_t)m*ND + tid      ], acc0);
    acc1 = fmaf(a, xb[(size_t)m*ND + tid + 256], acc1);
  }
  unsigned short h,l;
  fsplit(acc0,h,l); yh[base+tid]=h;     yl[base+tid]=l;
  fsplit(acc1,h,l); yh[base+tid+256]=h; yl[base+tid+256]=l;
}

// ---------------- W transpose + split: WT[h][d] ----------------
__global__ void __launch_bounds__(256) wsplit_kernel(const float* __restrict__ W,
                                                     unsigned short* __restrict__ WTh,
                                                     unsigned short* __restrict__ WTl){
  __shared__ float t[32][33];
  int bx = blockIdx.x, by = blockIdx.y;
  int x = threadIdx.x & 31, y = threadIdx.x >> 5;
  for (int yy=y; yy<32; yy+=8) t[yy][x] = W[(size_t)(bx*32+yy)*512 + by*32 + x];
  __syncthreads();
  for (int yy=y; yy<32; yy+=8){
    float v = t[x][yy];                     // = W[bx*32+x][by*32+yy]
    unsigned short h,l; fsplit(v,h,l);
    size_t idx = (size_t)(by*32+yy)*512 + bx*32 + x;
    WTh[idx]=h; WTl[idx]=l;
  }
}

// ---------------- masked softmax ----------------
// SPLIT: write bf16 h/l planes.  WF32: write f32 result in-place.
template<bool SPLIT, bool WF32>
__global__ void __launch_bounds__(256) softmax_kernel(float* __restrict__ s,
                                                      unsigned short* __restrict__ sh,
                                                      unsigned short* __restrict__ sl,
                                                      const int* __restrict__ cnum){
  int row  = blockIdx.x*4 + (threadIdx.x >> 6);
  int lane = threadIdx.x & 63;
  int b = row >> 11;
  int Kc = cnum[b];
  float* p = s + (size_t)row * NC;
  float4 v0 = *(const float4*)(p + lane*4);
  float4 v1 = *(const float4*)(p + lane*4 + 256);
  float e[8] = {v0.x,v0.y,v0.z,v0.w,v1.x,v1.y,v1.z,v1.w};
  float m = -3.0e38f;
  #pragma unroll
  for (int j=0;j<8;j++){
    int c = (j<4) ? lane*4 + j : lane*4 + 252 + j;
    if (c < Kc) m = fmaxf(m, e[j]);
  }
  #pragma unroll
  for (int off=32; off; off>>=1) m = fmaxf(m, __shfl_xor(m, off, 64));
  float r[8]; float sum = 0.f;
  #pragma unroll
  for (int j=0;j<8;j++){
    int c = (j<4) ? lane*4 + j : lane*4 + 252 + j;
    r[j] = (c < Kc) ? expf(e[j] - m) : 0.0f;
    sum += r[j];
  }
  #pragma unroll
  for (int off=32; off; off>>=1) sum += __shfl_xor(sum, off, 64);
  float inv = 1.0f / sum;
  #pragma unroll
  for (int j=0;j<8;j++) r[j] *= inv;
  if constexpr (WF32){
    *(float4*)(p + lane*4)       = make_float4(r[0],r[1],r[2],r[3]);
    *(float4*)(p + lane*4 + 256) = make_float4(r[4],r[5],r[6],r[7]);
  }
  if constexpr (SPLIT){
    unsigned long long ph=0, pl=0, qh=0, ql=0;
    #pragma unroll
    for (int j=0;j<4;j++){
      unsigned short h,l;
      fsplit(r[j],h,l);
      ph |= (unsigned long long)h << (16*j);  pl |= (unsigned long long)l << (16*j);
      fsplit(r[4+j],h,l);
      qh |= (unsigned long long)h << (16*j);  ql |= (unsigned long long)l << (16*j);
    }
    size_t base = (size_t)row * NC + lane*4;
    *(unsigned long long*)(sh + base)       = ph;
    *(unsigned long long*)(sl + base)       = pl;
    *(unsigned long long*)(sh + base + 256) = qh;
    *(unsigned long long*)(sl + base + 256) = ql;
  }
}

// ============ 256x256 8-wave split-bf16 GEMM, K-innermost operands ============
// C(m,n) = sum_k A[m][k]*B[n][k]   A: M x 512, B: N x 512 (both h+l planes)
// EPI 1: relu(acc+bias[n]) -> split OutH/OutL.
// EPI 2: Cf = (S2h+S2l) + scale[n]*acc   (S2 reconstructed from bf16 planes)
// Dead-strip skip: m-strips >= lim_m (rows where A==0) and n-strips >= lim_n.
template<int EPI, bool SWZ>
__global__ void __launch_bounds__(512,2) gemm256_kernel(
    const unsigned short* __restrict__ Ah, const unsigned short* __restrict__ Al,
    const unsigned short* __restrict__ Bh, const unsigned short* __restrict__ Bl,
    unsigned short* __restrict__ OutH, unsigned short* __restrict__ OutL,
    float* __restrict__ Cf, const unsigned short* __restrict__ S2h,
    const unsigned short* __restrict__ S2l,
    const float* __restrict__ bias, const float* __restrict__ scale,
    const int* __restrict__ lenbuf, const int* __restrict__ cnumbuf,
    int K, long sA, long sB, long sC)
{
  __shared__ __align__(16) unsigned char smem[131072];   // 2 x 64KB buffers
  int bx, by, bz;
  if constexpr (SWZ){          // XCD-chunked bijective remap (grid = 512, %8==0)
    int flat = blockIdx.x;
    int f2 = (flat & 7)*64 + (flat >> 3);
    bz = f2 >> 4; int rem = f2 & 15; bx = rem >> 1; by = rem & 1;
  } else { bx = blockIdx.x; by = blockIdx.y; bz = blockIdx.z; }
  Ah += (size_t)bz*sA; Al += (size_t)bz*sA;
  Bh += (size_t)bz*sB; Bl += (size_t)bz*sB;
  if constexpr (EPI==2){
    Cf += (size_t)bz*sC; S2h += (size_t)bz*sC; S2l += (size_t)bz*sC;
    scale += (size_t)bz*NC;
  }
  int m0 = bx*256, n0 = by*256;
  int lim_m, lim_n;
  if constexpr (EPI==1){
    lim_m = lenbuf[m0 >> 11] - (m0 & 2047);   // rows >= len: y==0
    lim_n = 256;
  } else {
    lim_m = lenbuf[bz] - m0;                  // rows >= len: z==0
    lim_n = cnumbuf[bz] - n0;                 // cols >= Kc: xn==0
  }
  int tid = threadIdx.x;
  int l = tid & 63, wid = tid >> 6;
  int wr = wid >> 2, wc = wid & 3;
  int lr = l & 15, lk = l >> 4;

  bool liA[8]; bool liB[4];
  int offA[8], offB[4];
  #pragma unroll
  for (int i=0;i<8;i++){
    int ra = wr*128 + i*16 + lr;
    offA[i] = ra*64 + ((lk ^ ((ra>>1)&3))<<4);
    liA[i] = (wr*128 + i*16) < lim_m;
  }
  #pragma unroll
  for (int j=0;j<4;j++){
    int rb = wc*64 + j*16 + lr;
    offB[j] = rb*64 + ((lk ^ ((rb>>1)&3))<<4);
    liB[j] = (wc*64 + j*16) < lim_n;
  }

  // staging: per matrix 256rows x 64B = 16KB = 2 issues of (512thr x 16B)
  int srow = tid >> 2;                          // 0..127
  int gslot = (tid & 3) ^ ((srow>>1)&3);        // pre-swizzled global k-slot
  const unsigned short* gA0 = Ah + (size_t)(m0 +       srow)*512 + gslot*8;
  const unsigned short* gA1 = Ah + (size_t)(m0 + 128 + srow)*512 + gslot*8;
  const unsigned short* gA2 = Al + (size_t)(m0 +       srow)*512 + gslot*8;
  const unsigned short* gA3 = Al + (size_t)(m0 + 128 + srow)*512 + gslot*8;
  const unsigned short* gB0 = Bh + (size_t)(n0 +       srow)*512 + gslot*8;
  const unsigned short* gB1 = Bh + (size_t)(n0 + 128 + srow)*512 + gslot*8;
  const unsigned short* gB2 = Bl + (size_t)(n0 +       srow)*512 + gslot*8;
  const unsigned short* gB3 = Bl + (size_t)(n0 + 128 + srow)*512 + gslot*8;

  f32x4 acc[8][4] = {};

#define STAGE256(buf, k0) { \
    unsigned char* db = smem + (buf)*65536 + wid*1024; \
    gload16(gA0 + (k0), db);          gload16(gA1 + (k0), db + 8192); \
    gload16(gA2 + (k0), db + 16384);  gload16(gA3 + (k0), db + 24576); \
    gload16(gB0 + (k0), db + 32768);  gload16(gB1 + (k0), db + 40960); \
    gload16(gB2 + (k0), db + 49152);  gload16(gB3 + (k0), db + 57344); }

  STAGE256(0, 0)
  __syncthreads();
  int KT = K >> 5;
  for (int t = 0; t < KT; ++t){
    if (t+1 < KT) STAGE256((t+1)&1, (t+1)*32)
    const unsigned char* base = smem + (t&1)*65536;
    short8v ah[8], bh[4], bl[4];
    #pragma unroll
    for (int i=0;i<8;i++) if (liA[i]) ah[i] = *(const short8v*)(base + offA[i]);
    #pragma unroll
    for (int j=0;j<4;j++) if (liB[j]){
      bh[j] = *(const short8v*)(base + 32768 + offB[j]);
      bl[j] = *(const short8v*)(base + 49152 + offB[j]);
    }
    #pragma unroll
    for (int i=0;i<8;i++) if (liA[i])
      #pragma unroll
      for (int j=0;j<4;j++) if (liB[j]) acc[i][j] = MFMA16(ah[i], bh[j], acc[i][j]);
    #pragma unroll
    for (int i=0;i<8;i++) if (liA[i])
      #pragma unroll
      for (int j=0;j<4;j++) if (liB[j]) acc[i][j] = MFMA16(ah[i], bl[j], acc[i][j]);
    #pragma unroll
    for (int i=0;i<8;i++) if (liA[i]){
      short8v al = *(const short8v*)(base + 16384 + offA[i]);
      #pragma unroll
      for (int j=0;j<4;j++) if (liB[j]) acc[i][j] = MFMA16(al, bh[j], acc[i][j]);
    }
    __syncthreads();
  }
#undef STAGE256

  // epilogue
  float aux[4];
  #pragma unroll
  for (int j=0;j<4;j++){
    int gcol = n0 + wc*64 + j*16 + lr;
    if constexpr (EPI==1) aux[j] = bias[gcol];
    if constexpr (EPI==2) aux[j] = scale[gcol];
  }
  #pragma unroll
  for (int i=0;i<8;i++){
    #pragma unroll
    for (int r=0;r<4;r++){
      int grow = m0 + wr*128 + i*16 + lk*4 + r;
      size_t rowb = (size_t)grow*512 + n0 + wc*64 + lr;
      #pragma unroll
      for (int j=0;j<4;j++){
        float v = acc[i][j][r];
        if constexpr (EPI==1){
          v = fmaxf(v + aux[j], 0.f);
          unsigned short h,lo2; fsplit(v,h,lo2);
          OutH[rowb + j*16] = h; OutL[rowb + j*16] = lo2;
        } else {
          unsigned hh = S2h[rowb + j*16], ll = S2l[rowb + j*16];
          float s2 = __uint_as_float(hh<<16) + __uint_as_float(ll<<16);
          Cf[rowb + j*16] = s2 + aux[j]*v;
        }
      }
    }
  }
}

// ============ GEMM2: xn[c][h] = sum_n st[n][c] z[n][h], 256x128 tile ============
// reg-staged transposed staging (T14 split). partials for squash.
// K clipped to ceil(len/32)*32 (z rows beyond are 0); c-strips >= Kc skipped.
__global__ void __launch_bounds__(512,2) gemmT256_kernel(
    const unsigned short* __restrict__ Ah, const unsigned short* __restrict__ Al,
    const unsigned short* __restrict__ Bh, const unsigned short* __restrict__ Bl,
    unsigned short* __restrict__ OutH, unsigned short* __restrict__ OutL,
    float* __restrict__ parts, const int* __restrict__ lenbuf,
    const int* __restrict__ cnumbuf)
{
  __shared__ __align__(16) unsigned char smem[98304];   // 2 x 48KB (A:16+16, B:8+8)
  int flat = blockIdx.x;                    // grid = 256, XCD-chunked remap
  int f2 = (flat & 7)*32 + (flat >> 3);
  int bz = f2 >> 3; int rem = f2 & 7; int bx = rem & 1; int by = rem >> 1;
  size_t boff = (size_t)bz * NN * 512;
  Ah += boff; Al += boff; Bh += boff; Bl += boff;
  int m0 = bx*256, n0 = by*128;
  int KT = (lenbuf[bz] + 31) >> 5;
  int limc = cnumbuf[bz] - m0;
  int tid = threadIdx.x;
  int l = tid & 63, wid = tid >> 6;
  int wr = wid >> 2, wc = wid & 3;          // wr: 128-c half, wc: 32-h strip
  int lr = l & 15, lk = l >> 4;

  bool liA[8];
  int offA[8], offB[2];
  #pragma unroll
  for (int i=0;i<8;i++){
    int ra = wr*128 + i*16 + lr;
    offA[i] = ra*64 + ((lk ^ ((ra>>1)&3) ^ ((ra>>3)&3))<<4);
    liA[i] = (wr*128 + i*16) < limc;
  }
  #pragma unroll
  for (int j=0;j<2;j++){
    int rb = wc*32 + j*16 + lr;
    offB[j] = rb*64 + ((lk ^ ((rb>>1)&3) ^ ((rb>>3)&3))<<4);
  }

  int np  = tid & 15;
  int seg = tid >> 4;          // 0..31 for A; 0..15 for B (tid<256)
  f32x4 acc[8][2] = {};

  short8v ra0h, ra1h, ra0l, ra1l, rb0h, rb1h, rb0l, rb1l;
  int have_b = (tid < 256);

#define TLOAD(k0) { \
    size_t ga = (size_t)((k0) + 2*np)*512 + m0 + seg*8; \
    ra0h = *(const short8v*)(Ah + ga); ra1h = *(const short8v*)(Ah + ga + 512); \
    ra0l = *(const short8v*)(Al + ga); ra1l = *(const short8v*)(Al + ga + 512); \
    if (have_b){ \
      size_t gb = (size_t)((k0) + 2*np)*512 + n0 + seg*8; \
      rb0h = *(const short8v*)(Bh + gb); rb1h = *(const short8v*)(Bh + gb + 512); \
      rb0l = *(const short8v*)(Bl + gb); rb1l = *(const short8v*)(Bl + gb + 512); } }

#define TWRITE(buf) { \
    unsigned char* bb = smem + (buf)*49152; \
    _Pragma("unroll") \
    for (int k=0;k<8;k++){ \
      int c = seg*8 + k; \
      int ps = (np>>2) ^ ((c>>1)&3) ^ ((c>>3)&3); \
      int byo = c*64 + ps*16 + (np&3)*4; \
      *(unsigned int*)(bb + byo)         = (unsigned int)(unsigned short)ra0h[k] | ((unsigned int)(unsigned short)ra1h[k]<<16); \
      *(unsigned int*)(bb + 16384 + byo) = (unsigned int)(unsigned short)ra0l[k] | ((unsigned int)(unsigned short)ra1l[k]<<16); \
      if (have_b){ \
        *(unsigned int*)(bb + 32768 + byo) = (unsigned int)(unsigned short)rb0h[k] | ((unsigned int)(unsigned short)rb1h[k]<<16); \
        *(unsigned int*)(bb + 40960 + byo) = (unsigned int)(unsigned short)rb0l[k] | ((unsigned int)(unsigned short)rb1l[k]<<16); } } }

  TLOAD(0)
  TWRITE(0)
  __syncthreads();
  for (int t = 0; t < KT; ++t){
    int more = (t+1 < KT);
    if (more) TLOAD((t+1)*32)
    const unsigned char* base = smem + (t&1)*49152;
    short8v ah[8], bh[2], bl[2];
    #pragma unroll
    for (int i=0;i<8;i++) if (liA[i]) ah[i] = *(const short8v*)(base + offA[i]);
    #pragma unroll
    for (int j=0;j<2;j++){
      bh[j] = *(const short8v*)(base + 32768 + offB[j]);
      bl[j] = *(const short8v*)(base + 40960 + offB[j]);
    }
    #pragma unroll
    for (int i=0;i<8;i++) if (liA[i])
      #pragma unroll
      for (int j=0;j<2;j++) acc[i][j] = MFMA16(ah[i], bh[j], acc[i][j]);
    #pragma unroll
    for (int i=0;i<8;i++) if (liA[i])
      #pragma unroll
      for (int j=0;j<2;j++) acc[i][j] = MFMA16(ah[i], bl[j], acc[i][j]);
    #pragma unroll
    for (int i=0;i<8;i++) if (liA[i]){
      short8v al = *(const short8v*)(base + 16384 + offA[i]);
      #pragma unroll
      for (int j=0;j<2;j++) acc[i][j] = MFMA16(al, bh[j], acc[i][j]);
    }
    if (more) TWRITE((t+1)&1)
    __syncthreads();
  }
#undef TLOAD
#undef TWRITE

  // epilogue: split store + per-c-row sum-of-squares partials
  #pragma unroll
  for (int i=0;i<8;i++){
    #pragma unroll
    for (int r=0;r<4;r++){
      int grow = m0 + wr*128 + i*16 + lk*4 + r;     // c index
      float p = 0.f;
      size_t rowb = (size_t)bz*NC*NH + (size_t)grow*512 + n0 + wc*32 + lr;
      #pragma unroll
      for (int j=0;j<2;j++){
        float v = acc[i][j][r];
        p = fmaf(v,v,p);
        unsigned short h,lo2; fsplit(v,h,lo2);
        OutH[rowb + j*16] = h; OutL[rowb + j*16] = lo2;
      }
      p += __shfl_xor(p, 1, 64);
      p += __shfl_xor(p, 2, 64);
      p += __shfl_xor(p, 4, 64);
      p += __shfl_xor(p, 8, 64);
      if (lr == 0) parts[(((size_t)bz*NC) + grow)*16 + by*4 + wc] = p;
    }
  }
}

// ---------------- squash scale from partials ----------------
__global__ void __launch_bounds__(512) scale_kernel(const float* __restrict__ parts,
                                                    float* __restrict__ scale){
  int b = blockIdx.x, c = threadIdx.x;
  const float* p = parts + ((size_t)b*NC + c)*16;
  float m2 = 0.f;
  #pragma unroll
  for (int j=0;j<16;j++) m2 += p[j];
  float sc = 0.0f;
  if (m2 > 0.0f) sc = (m2/(1.0f+m2)) / sqrtf(m2);
  scale[(size_t)b*NC + c] = sc;
}

// ---------------- orchestration ----------------
extern "C" void kernel_launch(void* const* d_in, const int* in_sizes, int n_in,
                              void* d_out, int out_size, void* d_ws, size_t ws_size,
                              hipStream_t stream) {
  const float* x    = (const float*)d_in[0];
  const float* adj  = (const float*)d_in[1];
  const float* W    = (const float*)d_in[2];
  const float* bias = (const float*)d_in[3];
  const unsigned char* mask = (const unsigned char*)d_in[4];
  float* out = (float*)d_out;                 // holds s (f32) and finally softmax(s)
  char* ws = (char*)d_ws;

  unsigned short* zh   = (unsigned short*)(ws);                 // 64 MB
  unsigned short* zl   = (unsigned short*)(ws + 67108864);      // 64 MB
  unsigned short* sth  = (unsigned short*)(ws + 134217728);     // 64 MB (aliases yh)
  unsigned short* stl  = (unsigned short*)(ws + 201326592);     // 64 MB (aliases yl)
  unsigned short* xnh  = (unsigned short*)(ws + 268435456);     // 16 MB
  unsigned short* xnl  = (unsigned short*)(ws + 285212672);     // 16 MB
  unsigned short* WTh  = (unsigned short*)(ws + 301989888);     // 0.5 MB
  unsigned short* WTl  = (unsigned short*)(ws + 302514176);     // 0.5 MB
  float* parts         = (float*)(ws + 303038464);              // 1 MB
  float* scalebuf      = (float*)(ws + 304087040);              // 64 KB
  int*   cnum          = (int*)(ws + 304152576);                // 128 B
  int*   lenbuf        = (int*)(ws + 304152704);                // 128 B
  unsigned short* yh = sth;
  unsigned short* yl = stl;

  counts_kernel<<<NB, 256, 0, stream>>>(mask, cnum, lenbuf);
  wsplit_kernel<<<dim3(16,16), 256, 0, stream>>>(W, WTh, WTl);
  spmm_kernel<<<ROWS, 256, 0, stream>>>(adj, x, yh, yl, lenbuf);
  // z = relu(y @ W + b): M=65536 N=512 K=512
  gemm256_kernel<1,false><<<dim3(256,2,1), 512, 0, stream>>>(
      yh, yl, WTh, WTl, zh, zl, nullptr, nullptr, nullptr, bias, nullptr,
      lenbuf, cnum, ND, 0, 0, 0);
  // s0 = jax.random.normal(key(42)) -> d_out
  rng_kernel<<<(ROWS*NC)/256, 256, 0, stream>>>(out);

  for (int it = 0; it < 3; ++it){
    // s~ = masked_softmax(s): split bf16 planes only (f32 s left stale)
    softmax_kernel<true,false><<<ROWS/4, 256, 0, stream>>>(out, sth, stl, cnum);
    // xn[c][h] = sum_n s~[n][c] z[n][h]  (+ c-row sumsq partials)
    gemmT256_kernel<<<256, 512, 0, stream>>>(
        sth, stl, zh, zl, xnh, xnl, parts, lenbuf, cnum);
    scale_kernel<<<NB, 512, 0, stream>>>(parts, scalebuf);
    // s = (sth+stl) + scale[c] * (z @ xn^T): M=2048 N=512 K=512 per batch
    gemm256_kernel<2,true><<<512, 512, 0, stream>>>(
        zh, zl, xnh, xnl, nullptr, nullptr, out, sth, stl, nullptr, scalebuf,
        lenbuf, cnum, NH, (long)NN*NH, (long)NC*NH, (long)NN*NC);
  }
  softmax_kernel<false,true><<<ROWS/4, 256, 0, stream>>>(out, nullptr, nullptr, cnum);
}

// Round 6
// 1417.161 us; speedup vs baseline: 2.2733x; 1.0351x over previous
//
#include <hip/hip_runtime.h>
#include <cstdint>
#include <cstddef>

#define NB 32
#define NN 2048
#define ND 512
#define NH 512
#define NC 512
#define ROWS (NB*NN)                 // 65536

typedef __attribute__((ext_vector_type(8))) short short8v;   // 8 bf16 (4 VGPR)
typedef __attribute__((ext_vector_type(4))) float f32x4;

#define MFMA16(a,b,c) __builtin_amdgcn_mfma_f32_16x16x32_bf16((a),(b),(c),0,0,0)

typedef const __attribute__((address_space(1))) unsigned int* gas_t;
typedef __attribute__((address_space(3))) unsigned int* las_t;

__device__ __forceinline__ void gload16(const void* g, void* l){
  __builtin_amdgcn_global_load_lds((gas_t)g, (las_t)l, 16, 0, 0);
}

// f32 -> bf16 hi/lo split (RNE both).  v ~= h + l, |v-h-l| <= 2^-18 |v|
__device__ __forceinline__ void fsplit(float v, unsigned short& h, unsigned short& l){
  unsigned u = __float_as_uint(v);
  unsigned hb = (u + 0x7FFFu + ((u>>16)&1u)) >> 16;
  float hf = __uint_as_float(hb<<16);
  float r = v - hf;
  unsigned ur = __float_as_uint(r);
  l = (unsigned short)((ur + 0x7FFFu + ((ur>>16)&1u)) >> 16);
  h = (unsigned short)hb;
}

// ---------------- threefry2x32-20 (JAX partitionable scheme) ----------------
__device__ __forceinline__ unsigned rotl32(unsigned x, int d){ return (x<<d)|(x>>(32-d)); }

__device__ __forceinline__ unsigned threefry_xor(unsigned k0, unsigned k1, unsigned c0, unsigned c1){
  unsigned ks2 = 0x1BD11BDAu ^ k0 ^ k1;
  unsigned x0 = c0 + k0, x1 = c1 + k1;
#define TF_RND(r) { x0 += x1; x1 = rotl32(x1,(r)); x1 ^= x0; }
  TF_RND(13) TF_RND(15) TF_RND(26) TF_RND(6)
  x0 += k1;  x1 += ks2 + 1u;
  TF_RND(17) TF_RND(29) TF_RND(16) TF_RND(24)
  x0 += ks2; x1 += k0 + 2u;
  TF_RND(13) TF_RND(15) TF_RND(26) TF_RND(6)
  x0 += k0;  x1 += k1 + 3u;
  TF_RND(17) TF_RND(29) TF_RND(16) TF_RND(24)
  x0 += k1;  x1 += ks2 + 4u;
  TF_RND(13) TF_RND(15) TF_RND(26) TF_RND(6)
  x0 += ks2; x1 += k0 + 5u;
#undef TF_RND
  return x0 ^ x1;
}

__device__ __forceinline__ float bits_to_normal(unsigned bits){
  float f = __uint_as_float((bits >> 9) | 0x3f800000u) - 1.0f;
  const float lo = -0.99999994f;
  float u = fmaxf(lo, fmaf(f, 2.0f, lo));
  float w = -log1pf(-(u*u));
  float p;
  if (w < 5.0f){
    w -= 2.5f;
    p =            2.81022636e-08f;
    p = fmaf(p, w, 3.43273939e-07f);
    p = fmaf(p, w, -3.5233877e-06f);
    p = fmaf(p, w, -4.39150654e-06f);
    p = fmaf(p, w, 0.00021858087f);
    p = fmaf(p, w, -0.00125372503f);
    p = fmaf(p, w, -0.00417768164f);
    p = fmaf(p, w, 0.246640727f);
    p = fmaf(p, w, 1.50140941f);
  } else {
    w = sqrtf(w) - 3.0f;
    p =            -0.000200214257f;
    p = fmaf(p, w, 0.000100950558f);
    p = fmaf(p, w, 0.00134934322f);
    p = fmaf(p, w, -0.00367342844f);
    p = fmaf(p, w, 0.00573950773f);
    p = fmaf(p, w, -0.0076224613f);
    p = fmaf(p, w, 0.00943887047f);
    p = fmaf(p, w, 1.00167406f);
    p = fmaf(p, w, 2.83297682f);
  }
  return 1.4142135623730951f * (p * u);
}

__global__ void __launch_bounds__(256) rng_kernel(float* __restrict__ s){
  unsigned i = blockIdx.x * 256u + threadIdx.x;
  s[i] = bits_to_normal(threefry_xor(0u, 42u, 0u, i));
}

// ---------------- cluster counts + lens ----------------
__global__ void __launch_bounds__(256) counts_kernel(const unsigned char* __restrict__ mraw,
                                                     int* __restrict__ cnum,
                                                     int* __restrict__ lenbuf){
  __shared__ int red[256];
  int b = blockIdx.x, tid = threadIdx.x;
  unsigned char b0 = mraw[0], b1 = mraw[1];
  int cnt = 0;
  if (b0 == 1 && b1 == 1){
    const unsigned char* p = mraw + (size_t)b * NN;
    for (int i = tid; i < NN; i += 256) cnt += (p[i] != 0);
  } else if (b0 == 1){
    const int* p = (const int*)mraw + (size_t)b * NN;
    for (int i = tid; i < NN; i += 256) cnt += (p[i] != 0);
  } else {
    const float* p = (const float*)mraw + (size_t)b * NN;
    for (int i = tid; i < NN; i += 256) cnt += (p[i] != 0.0f);
  }
  red[tid] = cnt; __syncthreads();
  for (int off = 128; off; off >>= 1){ if (tid < off) red[tid] += red[tid+off]; __syncthreads(); }
  if (tid == 0){ cnum[b] = red[0] >> 2; lenbuf[b] = red[0]; }
}

// ---------------- y = adj @ x, writes split bf16 (skips dead rows) ----------------
__global__ void __launch_bounds__(256) spmm_kernel(const float* __restrict__ adj,
                                                   const float* __restrict__ x,
                                                   unsigned short* __restrict__ yh,
                                                   unsigned short* __restrict__ yl,
                                                   const int* __restrict__ lenbuf){
  __shared__ int   idxs[NN];
  __shared__ float vals[NN];
  __shared__ int   scan[256];
  int row = blockIdx.x;
  int b = row >> 11;
  int n = row & 2047;
  int tid = threadIdx.x;
  size_t base = (size_t)row * ND;
  if (n >= lenbuf[b]){      // adj row is all-zero: y = 0 (skip 8KB adj read)
    yh[base+tid]=0; yl[base+tid]=0; yh[base+tid+256]=0; yl[base+tid+256]=0;
    return;
  }
  const float* arow = adj + (size_t)row * NN;
  float v[8];
  *(float4*)&v[0] = *(const float4*)(arow + tid*8);
  *(float4*)&v[4] = *(const float4*)(arow + tid*8 + 4);
  int lc = 0;
  #pragma unroll
  for (int j=0;j<8;j++) lc += (v[j] != 0.0f);
  scan[tid] = lc; __syncthreads();
  for (int off=1; off<256; off<<=1){
    int t = (tid >= off) ? scan[tid-off] : 0;
    __syncthreads();
    scan[tid] += t;
    __syncthreads();
  }
  int pos = scan[tid] - lc;
  int total = scan[255];
  #pragma unroll
  for (int j=0;j<8;j++){
    if (v[j] != 0.0f){ idxs[pos] = tid*8 + j; vals[pos] = v[j]; pos++; }
  }
  __syncthreads();
  float acc0 = 0.f, acc1 = 0.f;
  const float* xb = x + (size_t)b * NN * ND;
  for (int j=0;j<total;j++){
    int m = idxs[j]; float a = vals[j];
    acc0 = fmaf(a, xb[(size_t)m*ND + tid      ], acc0);
    acc1 = fmaf(a, xb[(size_t)m*ND + tid + 256], acc1);
  }
  unsigned short h,l;
  fsplit(acc0,h,l); yh[base+tid]=h;     yl[base+tid]=l;
  fsplit(acc1,h,l); yh[base+tid+256]=h; yl[base+tid+256]=l;
}

// ---------------- W transpose + split: WT[h][d] ----------------
__global__ void __launch_bounds__(256) wsplit_kernel(const float* __restrict__ W,
                                                     unsigned short* __restrict__ WTh,
                                                     unsigned short* __restrict__ WTl){
  __shared__ float t[32][33];
  int bx = blockIdx.x, by = blockIdx.y;
  int x = threadIdx.x & 31, y = threadIdx.x >> 5;
  for (int yy=y; yy<32; yy+=8) t[yy][x] = W[(size_t)(bx*32+yy)*512 + by*32 + x];
  __syncthreads();
  for (int yy=y; yy<32; yy+=8){
    float v = t[x][yy];                     // = W[bx*32+x][by*32+yy]
    unsigned short h,l; fsplit(v,h,l);
    size_t idx = (size_t)(by*32+yy)*512 + bx*32 + x;
    WTh[idx]=h; WTl[idx]=l;
  }
}

// ---------------- masked softmax ----------------
// SPLIT: write bf16 h/l planes.  WF32: write f32 result in-place.
template<bool SPLIT, bool WF32>
__global__ void __launch_bounds__(256) softmax_kernel(float* __restrict__ s,
                                                      unsigned short* __restrict__ sh,
                                                      unsigned short* __restrict__ sl,
                                                      const int* __restrict__ cnum){
  int row  = blockIdx.x*4 + (threadIdx.x >> 6);
  int lane = threadIdx.x & 63;
  int b = row >> 11;
  int Kc = cnum[b];
  float* p = s + (size_t)row * NC;
  float4 v0 = *(const float4*)(p + lane*4);
  float4 v1 = *(const float4*)(p + lane*4 + 256);
  float e[8] = {v0.x,v0.y,v0.z,v0.w,v1.x,v1.y,v1.z,v1.w};
  float m = -3.0e38f;
  #pragma unroll
  for (int j=0;j<8;j++){
    int c = (j<4) ? lane*4 + j : lane*4 + 252 + j;
    if (c < Kc) m = fmaxf(m, e[j]);
  }
  #pragma unroll
  for (int off=32; off; off>>=1) m = fmaxf(m, __shfl_xor(m, off, 64));
  float r[8]; float sum = 0.f;
  #pragma unroll
  for (int j=0;j<8;j++){
    int c = (j<4) ? lane*4 + j : lane*4 + 252 + j;
    r[j] = (c < Kc) ? expf(e[j] - m) : 0.0f;
    sum += r[j];
  }
  #pragma unroll
  for (int off=32; off; off>>=1) sum += __shfl_xor(sum, off, 64);
  float inv = 1.0f / sum;
  #pragma unroll
  for (int j=0;j<8;j++) r[j] *= inv;
  if constexpr (WF32){
    *(float4*)(p + lane*4)       = make_float4(r[0],r[1],r[2],r[3]);
    *(float4*)(p + lane*4 + 256) = make_float4(r[4],r[5],r[6],r[7]);
  }
  if constexpr (SPLIT){
    unsigned long long ph=0, pl=0, qh=0, ql=0;
    #pragma unroll
    for (int j=0;j<4;j++){
      unsigned short h,l;
      fsplit(r[j],h,l);
      ph |= (unsigned long long)h << (16*j);  pl |= (unsigned long long)l << (16*j);
      fsplit(r[4+j],h,l);
      qh |= (unsigned long long)h << (16*j);  ql |= (unsigned long long)l << (16*j);
    }
    size_t base = (size_t)row * NC + lane*4;
    *(unsigned long long*)(sh + base)       = ph;
    *(unsigned long long*)(sl + base)       = pl;
    *(unsigned long long*)(sh + base + 256) = qh;
    *(unsigned long long*)(sl + base + 256) = ql;
  }
}

// ============ 256x256 8-wave split-bf16 GEMM, K-innermost operands ============
// C(m,n) = sum_k A[m][k]*B[n][k]   A: M x 512, B: N x 512 (both h+l planes)
// EPI 1: relu(acc+bias[n]) -> split OutH/OutL.
// EPI 2: Cf = (S2h+S2l) + scale[n]*acc   (S2 reconstructed from bf16 planes)
// Single 64KB LDS buffer -> 2 blocks/CU; front-loaded fragment reads; stage
// of tile t+1 issued after the read-barrier so HBM latency hides under MFMAs,
// and the vmcnt drain of one block overlaps the other block's compute.
template<int EPI, bool SWZ>
__global__ void __launch_bounds__(512,2) gemm256_kernel(
    const unsigned short* __restrict__ Ah, const unsigned short* __restrict__ Al,
    const unsigned short* __restrict__ Bh, const unsigned short* __restrict__ Bl,
    unsigned short* __restrict__ OutH, unsigned short* __restrict__ OutL,
    float* __restrict__ Cf, const unsigned short* __restrict__ S2h,
    const unsigned short* __restrict__ S2l,
    const float* __restrict__ bias, const float* __restrict__ scale,
    int K, long sA, long sB, long sC)
{
  __shared__ __align__(16) unsigned char smem[65536];   // Ah:0 Al:16K Bh:32K Bl:48K
  int bx, by, bz;
  if constexpr (SWZ){          // XCD-chunked bijective remap (grid = 512, %8==0)
    int flat = blockIdx.x;
    int f2 = (flat & 7)*64 + (flat >> 3);
    bz = f2 >> 4; int rem = f2 & 15; bx = rem >> 1; by = rem & 1;
  } else { bx = blockIdx.x; by = blockIdx.y; bz = blockIdx.z; }
  Ah += (size_t)bz*sA; Al += (size_t)bz*sA;
  Bh += (size_t)bz*sB; Bl += (size_t)bz*sB;
  if constexpr (EPI==2){
    Cf += (size_t)bz*sC; S2h += (size_t)bz*sC; S2l += (size_t)bz*sC;
    scale += (size_t)bz*NC;
  }
  int m0 = bx*256, n0 = by*256;
  int tid = threadIdx.x;
  int l = tid & 63, wid = tid >> 6;
  int wr = wid >> 2, wc = wid & 3;
  int lr = l & 15, lk = l >> 4;

  // fragment read offsets within a 16KB matrix region (256 rows x 64B)
  int offA[8], offB[4];
  #pragma unroll
  for (int i=0;i<8;i++){
    int ra = wr*128 + i*16 + lr;
    offA[i] = ra*64 + ((lk ^ ((ra>>1)&3))<<4);
  }
  #pragma unroll
  for (int j=0;j<4;j++){
    int rb = wc*64 + j*16 + lr;
    offB[j] = rb*64 + ((lk ^ ((rb>>1)&3))<<4);
  }

  // staging: per matrix-half 128rows x 64B = 8KB = 1 issue of (512thr x 16B)
  int srow = tid >> 2;                          // 0..127
  int gslot = (tid & 3) ^ ((srow>>1)&3);        // pre-swizzled global k-slot
  const unsigned short* gA0 = Ah + (size_t)(m0 +       srow)*512 + gslot*8;
  const unsigned short* gA1 = Ah + (size_t)(m0 + 128 + srow)*512 + gslot*8;
  const unsigned short* gA2 = Al + (size_t)(m0 +       srow)*512 + gslot*8;
  const unsigned short* gA3 = Al + (size_t)(m0 + 128 + srow)*512 + gslot*8;
  const unsigned short* gB0 = Bh + (size_t)(n0 +       srow)*512 + gslot*8;
  const unsigned short* gB1 = Bh + (size_t)(n0 + 128 + srow)*512 + gslot*8;
  const unsigned short* gB2 = Bl + (size_t)(n0 +       srow)*512 + gslot*8;
  const unsigned short* gB3 = Bl + (size_t)(n0 + 128 + srow)*512 + gslot*8;

  f32x4 acc[8][4] = {};

#define STAGE1(k0) { \
    unsigned char* db = smem + wid*1024; \
    gload16(gA0 + (k0), db);          gload16(gA1 + (k0), db + 8192); \
    gload16(gA2 + (k0), db + 16384);  gload16(gA3 + (k0), db + 24576); \
    gload16(gB0 + (k0), db + 32768);  gload16(gB1 + (k0), db + 40960); \
    gload16(gB2 + (k0), db + 49152);  gload16(gB3 + (k0), db + 57344); }

  STAGE1(0)
  int KT = K >> 5;
  for (int t = 0; t < KT; ++t){
    asm volatile("s_waitcnt vmcnt(0)" ::: "memory");   // this wave's stage done
    __syncthreads();                                   // all waves' stage done
    short8v ah[8], al[8], bh[4], bl[4];
    #pragma unroll
    for (int i=0;i<8;i++){
      ah[i] = *(const short8v*)(smem + offA[i]);
      al[i] = *(const short8v*)(smem + 16384 + offA[i]);
    }
    #pragma unroll
    for (int j=0;j<4;j++){
      bh[j] = *(const short8v*)(smem + 32768 + offB[j]);
      bl[j] = *(const short8v*)(smem + 49152 + offB[j]);
    }
    __syncthreads();                 // all waves done reading -> safe to overwrite
    if (t+1 < KT) STAGE1((t+1)*32)   // async loads fly under the MFMA phase
    __builtin_amdgcn_s_setprio(1);
    #pragma unroll
    for (int i=0;i<8;i++)
      #pragma unroll
      for (int j=0;j<4;j++) acc[i][j] = MFMA16(ah[i], bh[j], acc[i][j]);
    #pragma unroll
    for (int i=0;i<8;i++)
      #pragma unroll
      for (int j=0;j<4;j++) acc[i][j] = MFMA16(ah[i], bl[j], acc[i][j]);
    #pragma unroll
    for (int i=0;i<8;i++)
      #pragma unroll
      for (int j=0;j<4;j++) acc[i][j] = MFMA16(al[i], bh[j], acc[i][j]);
    __builtin_amdgcn_s_setprio(0);
  }
#undef STAGE1

  // epilogue
  float aux[4];
  #pragma unroll
  for (int j=0;j<4;j++){
    int gcol = n0 + wc*64 + j*16 + lr;
    if constexpr (EPI==1) aux[j] = bias[gcol];
    if constexpr (EPI==2) aux[j] = scale[gcol];
  }
  #pragma unroll
  for (int i=0;i<8;i++){
    #pragma unroll
    for (int r=0;r<4;r++){
      int grow = m0 + wr*128 + i*16 + lk*4 + r;
      size_t rowb = (size_t)grow*512 + n0 + wc*64 + lr;
      #pragma unroll
      for (int j=0;j<4;j++){
        float v = acc[i][j][r];
        if constexpr (EPI==1){
          v = fmaxf(v + aux[j], 0.f);
          unsigned short h,lo2; fsplit(v,h,lo2);
          OutH[rowb + j*16] = h; OutL[rowb + j*16] = lo2;
        } else {
          unsigned hh = S2h[rowb + j*16], ll = S2l[rowb + j*16];
          float s2 = __uint_as_float(hh<<16) + __uint_as_float(ll<<16);
          Cf[rowb + j*16] = s2 + aux[j]*v;
        }
      }
    }
  }
}

// ============ GEMM2: xn[c][h] = sum_n st[n][c] z[n][h], 256x128 tile ============
// reg-staged transposed staging (T14 split). partials for squash.
// K clipped to ceil(len/32)*32 (z rows beyond are 0); c-strips >= Kc skipped.
__global__ void __launch_bounds__(512,2) gemmT256_kernel(
    const unsigned short* __restrict__ Ah, const unsigned short* __restrict__ Al,
    const unsigned short* __restrict__ Bh, const unsigned short* __restrict__ Bl,
    unsigned short* __restrict__ OutH, unsigned short* __restrict__ OutL,
    float* __restrict__ parts, const int* __restrict__ lenbuf,
    const int* __restrict__ cnumbuf)
{
  __shared__ __align__(16) unsigned char smem[98304];   // 2 x 48KB (A:16+16, B:8+8)
  int flat = blockIdx.x;                    // grid = 256, XCD-chunked remap
  int f2 = (flat & 7)*32 + (flat >> 3);
  int bz = f2 >> 3; int rem = f2 & 7; int bx = rem & 1; int by = rem >> 1;
  size_t boff = (size_t)bz * NN * 512;
  Ah += boff; Al += boff; Bh += boff; Bl += boff;
  int m0 = bx*256, n0 = by*128;
  int KT = (lenbuf[bz] + 31) >> 5;
  int limc = cnumbuf[bz] - m0;
  int tid = threadIdx.x;
  int l = tid & 63, wid = tid >> 6;
  int wr = wid >> 2, wc = wid & 3;          // wr: 128-c half, wc: 32-h strip
  int lr = l & 15, lk = l >> 4;

  bool liA[8];
  int offA[8], offB[2];
  #pragma unroll
  for (int i=0;i<8;i++){
    int ra = wr*128 + i*16 + lr;
    offA[i] = ra*64 + ((lk ^ ((ra>>1)&3) ^ ((ra>>3)&3))<<4);
    liA[i] = (wr*128 + i*16) < limc;
  }
  #pragma unroll
  for (int j=0;j<2;j++){
    int rb = wc*32 + j*16 + lr;
    offB[j] = rb*64 + ((lk ^ ((rb>>1)&3) ^ ((rb>>3)&3))<<4);
  }

  int np  = tid & 15;
  int seg = tid >> 4;          // 0..31 for A; 0..15 for B (tid<256)
  f32x4 acc[8][2] = {};

  short8v ra0h, ra1h, ra0l, ra1l, rb0h, rb1h, rb0l, rb1l;
  int have_b = (tid < 256);

#define TLOAD(k0) { \
    size_t ga = (size_t)((k0) + 2*np)*512 + m0 + seg*8; \
    ra0h = *(const short8v*)(Ah + ga); ra1h = *(const short8v*)(Ah + ga + 512); \
    ra0l = *(const short8v*)(Al + ga); ra1l = *(const short8v*)(Al + ga + 512); \
    if (have_b){ \
      size_t gb = (size_t)((k0) + 2*np)*512 + n0 + seg*8; \
      rb0h = *(const short8v*)(Bh + gb); rb1h = *(const short8v*)(Bh + gb + 512); \
      rb0l = *(const short8v*)(Bl + gb); rb1l = *(const short8v*)(Bl + gb + 512); } }

#define TWRITE(buf) { \
    unsigned char* bb = smem + (buf)*49152; \
    _Pragma("unroll") \
    for (int k=0;k<8;k++){ \
      int c = seg*8 + k; \
      int ps = (np>>2) ^ ((c>>1)&3) ^ ((c>>3)&3); \
      int byo = c*64 + ps*16 + (np&3)*4; \
      *(unsigned int*)(bb + byo)         = (unsigned int)(unsigned short)ra0h[k] | ((unsigned int)(unsigned short)ra1h[k]<<16); \
      *(unsigned int*)(bb + 16384 + byo) = (unsigned int)(unsigned short)ra0l[k] | ((unsigned int)(unsigned short)ra1l[k]<<16); \
      if (have_b){ \
        *(unsigned int*)(bb + 32768 + byo) = (unsigned int)(unsigned short)rb0h[k] | ((unsigned int)(unsigned short)rb1h[k]<<16); \
        *(unsigned int*)(bb + 40960 + byo) = (unsigned int)(unsigned short)rb0l[k] | ((unsigned int)(unsigned short)rb1l[k]<<16); } } }

  TLOAD(0)
  TWRITE(0)
  __syncthreads();
  for (int t = 0; t < KT; ++t){
    int more = (t+1 < KT);
    if (more) TLOAD((t+1)*32)
    const unsigned char* base = smem + (t&1)*49152;
    short8v ah[8], bh[2], bl[2];
    #pragma unroll
    for (int i=0;i<8;i++) if (liA[i]) ah[i] = *(const short8v*)(base + offA[i]);
    #pragma unroll
    for (int j=0;j<2;j++){
      bh[j] = *(const short8v*)(base + 32768 + offB[j]);
      bl[j] = *(const short8v*)(base + 40960 + offB[j]);
    }
    #pragma unroll
    for (int i=0;i<8;i++) if (liA[i])
      #pragma unroll
      for (int j=0;j<2;j++) acc[i][j] = MFMA16(ah[i], bh[j], acc[i][j]);
    #pragma unroll
    for (int i=0;i<8;i++) if (liA[i])
      #pragma unroll
      for (int j=0;j<2;j++) acc[i][j] = MFMA16(ah[i], bl[j], acc[i][j]);
    #pragma unroll
    for (int i=0;i<8;i++) if (liA[i]){
      short8v al = *(const short8v*)(base + 16384 + offA[i]);
      #pragma unroll
      for (int j=0;j<2;j++) acc[i][j] = MFMA16(al, bh[j], acc[i][j]);
    }
    if (more) TWRITE((t+1)&1)
    __syncthreads();
  }
#undef TLOAD
#undef TWRITE

  // epilogue: split store + per-c-row sum-of-squares partials
  #pragma unroll
  for (int i=0;i<8;i++){
    #pragma unroll
    for (int r=0;r<4;r++){
      int grow = m0 + wr*128 + i*16 + lk*4 + r;     // c index
      float p = 0.f;
      size_t rowb = (size_t)bz*NC*NH + (size_t)grow*512 + n0 + wc*32 + lr;
      #pragma unroll
      for (int j=0;j<2;j++){
        float v = acc[i][j][r];
        p = fmaf(v,v,p);
        unsigned short h,lo2; fsplit(v,h,lo2);
        OutH[rowb + j*16] = h; OutL[rowb + j*16] = lo2;
      }
      p += __shfl_xor(p, 1, 64);
      p += __shfl_xor(p, 2, 64);
      p += __shfl_xor(p, 4, 64);
      p += __shfl_xor(p, 8, 64);
      if (lr == 0) parts[(((size_t)bz*NC) + grow)*16 + by*4 + wc] = p;
    }
  }
}

// ---------------- squash scale from partials ----------------
__global__ void __launch_bounds__(512) scale_kernel(const float* __restrict__ parts,
                                                    float* __restrict__ scale){
  int b = blockIdx.x, c = threadIdx.x;
  const float* p = parts + ((size_t)b*NC + c)*16;
  float m2 = 0.f;
  #pragma unroll
  for (int j=0;j<16;j++) m2 += p[j];
  float sc = 0.0f;
  if (m2 > 0.0f) sc = (m2/(1.0f+m2)) / sqrtf(m2);
  scale[(size_t)b*NC + c] = sc;
}

// ---------------- orchestration ----------------
extern "C" void kernel_launch(void* const* d_in, const int* in_sizes, int n_in,
                              void* d_out, int out_size, void* d_ws, size_t ws_size,
                              hipStream_t stream) {
  const float* x    = (const float*)d_in[0];
  const float* adj  = (const float*)d_in[1];
  const float* W    = (const float*)d_in[2];
  const float* bias = (const float*)d_in[3];
  const unsigned char* mask = (const unsigned char*)d_in[4];
  float* out = (float*)d_out;                 // holds s (f32) and finally softmax(s)
  char* ws = (char*)d_ws;

  unsigned short* zh   = (unsigned short*)(ws);                 // 64 MB
  unsigned short* zl   = (unsigned short*)(ws + 67108864);      // 64 MB
  unsigned short* sth  = (unsigned short*)(ws + 134217728);     // 64 MB (aliases yh)
  unsigned short* stl  = (unsigned short*)(ws + 201326592);     // 64 MB (aliases yl)
  unsigned short* xnh  = (unsigned short*)(ws + 268435456);     // 16 MB
  unsigned short* xnl  = (unsigned short*)(ws + 285212672);     // 16 MB
  unsigned short* WTh  = (unsigned short*)(ws + 301989888);     // 0.5 MB
  unsigned short* WTl  = (unsigned short*)(ws + 302514176);     // 0.5 MB
  float* parts         = (float*)(ws + 303038464);              // 1 MB
  float* scalebuf      = (float*)(ws + 304087040);              // 64 KB
  int*   cnum          = (int*)(ws + 304152576);                // 128 B
  int*   lenbuf        = (int*)(ws + 304152704);                // 128 B
  unsigned short* yh = sth;
  unsigned short* yl = stl;

  counts_kernel<<<NB, 256, 0, stream>>>(mask, cnum, lenbuf);
  wsplit_kernel<<<dim3(16,16), 256, 0, stream>>>(W, WTh, WTl);
  spmm_kernel<<<ROWS, 256, 0, stream>>>(adj, x, yh, yl, lenbuf);
  // z = relu(y @ W + b): M=65536 N=512 K=512
  gemm256_kernel<1,false><<<dim3(256,2,1), 512, 0, stream>>>(
      yh, yl, WTh, WTl, zh, zl, nullptr, nullptr, nullptr, bias, nullptr,
      ND, 0, 0, 0);
  // s0 = jax.random.normal(key(42)) -> d_out
  rng_kernel<<<(ROWS*NC)/256, 256, 0, stream>>>(out);

  for (int it = 0; it < 3; ++it){
    // s~ = masked_softmax(s): split bf16 planes only (f32 s left stale)
    softmax_kernel<true,false><<<ROWS/4, 256, 0, stream>>>(out, sth, stl, cnum);
    // xn[c][h] = sum_n s~[n][c] z[n][h]  (+ c-row sumsq partials)
    gemmT256_kernel<<<256, 512, 0, stream>>>(
        sth, stl, zh, zl, xnh, xnl, parts, lenbuf, cnum);
    scale_kernel<<<NB, 512, 0, stream>>>(parts, scalebuf);
    // s = (sth+stl) + scale[c] * (z @ xn^T): M=2048 N=512 K=512 per batch
    gemm256_kernel<2,true><<<512, 512, 0, stream>>>(
        zh, zl, xnh, xnl, nullptr, nullptr, out, sth, stl, nullptr, scalebuf,
        NH, (long)NN*NH, (long)NC*NH, (long)NN*NC);
  }
  softmax_kernel<false,true><<<ROWS/4, 256, 0, stream>>>(out, nullptr, nullptr, cnum);
}